// Round 1
// baseline (3599.081 us; speedup 1.0000x reference)
//
#include <hip/hip_runtime.h>
#include <hip/hip_bf16.h>
#include <cmath>

typedef __hip_bfloat16 bf16;
typedef __attribute__((ext_vector_type(8))) short short8;
typedef __attribute__((ext_vector_type(4))) float f32x4;
typedef __attribute__((address_space(1))) void as1_void;
typedef __attribute__((address_space(3))) void as3_void;

#define DE   2560
#define HD   512
#define NPAD 30016
#define QNUM 200
#define ADHD 320

static __device__ __forceinline__ float bf2f(bf16 v){ return __bfloat162float(v); }
static __device__ __forceinline__ bf16  f2bf(float v){ return __float2bfloat16(v); }
static __device__ __forceinline__ float geluf(float x){ return 0.5f*x*(1.0f+erff(x*0.70710678118654752440f)); }
static __device__ __forceinline__ float eluf(float x){ return x>0.f ? x : expm1f(x); }

static __device__ __forceinline__ void gload16(const void* g, void* l){
  __builtin_amdgcn_global_load_lds((as1_void*)g, (as3_void*)l, 16, 0, 0);
}

// ---------------- generic bf16 NT GEMM: C[M,N] = A[M,K] * B[N,K]^T ----------------
// ACT: 0 none, 1 gelu, 2 elu. OBF: 0 f32 store, 1 bf16 store, 2 f32 atomicAdd (no bias/act).
// TROUT: store C[col*ldc+row] instead of C[row*ldc+col].
template<int ACT, int BIAS, int OBF, int TROUT>
__global__ __launch_bounds__(256)
void k_gemm_nt(const bf16* __restrict__ A, const bf16* __restrict__ B,
               const float* __restrict__ bias, void* __restrict__ Cv,
               int M, int N, int K, int lda, int ldb, int ldc,
               long long sA, long long sB, long long sC, int nsplit, int ks)
{
  __shared__ __align__(16) bf16 As[128*32];
  __shared__ __align__(16) bf16 Bs[128*32];
  const int zb = blockIdx.z;
  const int b  = zb / nsplit;
  const int sl = zb - b*nsplit;
  const int kbeg = sl * ks;
  int kend = kbeg + ks; if (kend > K) kend = K;

  const bf16* Ab = A + (long long)b * sA;
  const bf16* Bb = B + (long long)b * sB;
  const long long cbase = (long long)b * sC;

  const int m0 = blockIdx.y * 128, n0 = blockIdx.x * 128;
  const int tid = threadIdx.x, lane = tid & 63, wave = tid >> 6;
  const int wm = (wave >> 1) * 64, wn = (wave & 1) * 64;
  const int fr = lane & 15, fg = lane >> 4;

  f32x4 acc[4][4];
  #pragma unroll
  for (int i = 0; i < 4; i++)
    #pragma unroll
    for (int j = 0; j < 4; j++) acc[i][j] = (f32x4){0.f, 0.f, 0.f, 0.f};

  // staging geometry: per wave 2 chunks-of-64 for A and for B
  const int c0 = wave * 128 + lane;       // chunk id (16B units) first inst
  const int c1 = c0 + 64;
  const int rowA0 = c0 >> 2, cc0 = (c0 & 3) * 8;
  const int rowA1 = c1 >> 2, cc1 = (c1 & 3) * 8;
  int gra0 = m0 + rowA0; if (gra0 >= M) gra0 = M - 1;
  int gra1 = m0 + rowA1; if (gra1 >= M) gra1 = M - 1;
  int grb0 = n0 + rowA0; if (grb0 >= N) grb0 = N - 1;
  int grb1 = n0 + rowA1; if (grb1 >= N) grb1 = N - 1;
  const bf16* pa0 = Ab + (long long)gra0 * lda + cc0;
  const bf16* pa1 = Ab + (long long)gra1 * lda + cc1;
  const bf16* pb0 = Bb + (long long)grb0 * ldb + cc0;
  const bf16* pb1 = Bb + (long long)grb1 * ldb + cc1;
  char* lA0 = (char*)As + (size_t)(wave * 2) * 1024;
  char* lA1 = lA0 + 1024;
  char* lB0 = (char*)Bs + (size_t)(wave * 2) * 1024;
  char* lB1 = lB0 + 1024;

  for (int k0 = kbeg; k0 < kend; k0 += 32) {
    __syncthreads();
    gload16(pa0 + k0, lA0);
    gload16(pa1 + k0, lA1);
    gload16(pb0 + k0, lB0);
    gload16(pb1 + k0, lB1);
    __syncthreads();
    short8 af[4], bfv[4];
    #pragma unroll
    for (int i = 0; i < 4; i++) {
      af[i]  = *(const short8*)(As + (wm + i * 16 + fr) * 32 + fg * 8);
      bfv[i] = *(const short8*)(Bs + (wn + i * 16 + fr) * 32 + fg * 8);
    }
    #pragma unroll
    for (int i = 0; i < 4; i++)
      #pragma unroll
      for (int j = 0; j < 4; j++)
        acc[i][j] = __builtin_amdgcn_mfma_f32_16x16x32_bf16(af[i], bfv[j], acc[i][j], 0, 0, 0);
  }

  #pragma unroll
  for (int i = 0; i < 4; i++) {
    const int r0 = m0 + wm + i * 16 + fg * 4;
    #pragma unroll
    for (int j = 0; j < 4; j++) {
      const int col = n0 + wn + j * 16 + fr;
      if (col >= N) continue;
      float bv = 0.f;
      if (BIAS) bv = bias[col];
      #pragma unroll
      for (int r = 0; r < 4; r++) {
        const int row = r0 + r;
        if (row >= M) continue;
        float v = acc[i][j][r] + bv;
        if (ACT == 1) v = geluf(v);
        else if (ACT == 2) v = eluf(v);
        long long off;
        if (TROUT) off = cbase + (long long)col * ldc + row;
        else       off = cbase + (long long)row * ldc + col;
        if (OBF == 1)      ((bf16*)Cv)[off] = f2bf(v);
        else if (OBF == 2) atomicAdd(&((float*)Cv)[off], v);
        else               ((float*)Cv)[off] = v;
      }
    }
  }
}

// ---------------- small utility kernels ----------------
__global__ void k_zero(float* p, long long n) {
  long long i = (long long)blockIdx.x * blockDim.x + threadIdx.x;
  long long st = (long long)gridDim.x * blockDim.x;
  for (; i < n; i += st) p[i] = 0.f;
}

__global__ void k_f2bf(const float* __restrict__ in, bf16* __restrict__ out, long long n) {
  long long i = (long long)blockIdx.x * 256 + threadIdx.x;
  if (i < n) out[i] = f2bf(in[i]);
}

__global__ void k_add_emb(const float* __restrict__ x, const float* __restrict__ ns,
                          bf16* __restrict__ h0) {
  int d = blockIdx.x * 256 + threadIdx.x;
  long long n = blockIdx.y;
  h0[n * DE + d] = f2bf(x[n * DE + d] + ns[d]);
}

// transpose f32 [R,C] -> bf16 [C,R]; R,C multiples of 32
__global__ void k_transpose_bf(const float* __restrict__ W, bf16* __restrict__ Wt, int R, int C) {
  __shared__ float t[32][33];
  int c0 = blockIdx.x * 32, r0 = blockIdx.y * 32;
  int x = threadIdx.x, y = threadIdx.y;
  #pragma unroll
  for (int j = 0; j < 32; j += 8)
    t[y + j][x] = W[(long long)(r0 + y + j) * C + c0 + x];
  __syncthreads();
  #pragma unroll
  for (int j = 0; j < 32; j += 8)
    Wt[(long long)(c0 + y + j) * R + r0 + x] = f2bf(t[x][y + j]);
}

// es/ed per node: block = 512 threads, wave w = head
__global__ __launch_bounds__(512)
void k_esed(const bf16* __restrict__ hh, const float* __restrict__ asrc,
            const float* __restrict__ adst, float* __restrict__ es, float* __restrict__ ed) {
  int n = blockIdx.x;
  int h = threadIdx.x >> 6;
  int c = threadIdx.x & 63;
  float v = bf2f(hh[(long long)n * HD + h * 64 + c]);
  float s = v * asrc[h * 64 + c];
  float d = v * adst[h * 64 + c];
  #pragma unroll
  for (int o = 32; o; o >>= 1) { s += __shfl_down(s, o, 64); d += __shfl_down(d, o, 64); }
  if (c == 0) { es[n * 8 + h] = s; ed[n * 8 + h] = d; }
}

__global__ void k_edge_logits(const int* __restrict__ ei, int E, int TOT,
                              const float* __restrict__ es, const float* __restrict__ ed,
                              float* __restrict__ logits, unsigned* __restrict__ mkey) {
  int e = blockIdx.x * 256 + threadIdx.x;
  if (e >= TOT) return;
  int s, d;
  if (e < E) { s = ei[e]; d = ei[E + e]; } else { s = d = e - E; }
  #pragma unroll
  for (int h = 0; h < 8; h++) {
    float l = es[s * 8 + h] + ed[d * 8 + h];
    l = l > 0.f ? l : 0.2f * l;
    logits[(long long)e * 8 + h] = l;
    unsigned u = __float_as_uint(l);
    unsigned key = (u & 0x80000000u) ? ~u : (u | 0x80000000u);
    atomicMax(&mkey[d * 8 + h], key);
  }
}

__global__ void k_edge_exp(const int* __restrict__ ei, int E, int TOT,
                           const unsigned* __restrict__ mkey, float* __restrict__ logits,
                           float* __restrict__ den) {
  int e = blockIdx.x * 256 + threadIdx.x;
  if (e >= TOT) return;
  int d = (e < E) ? ei[E + e] : (e - E);
  #pragma unroll
  for (int h = 0; h < 8; h++) {
    unsigned key = mkey[d * 8 + h];
    unsigned u = (key & 0x80000000u) ? (key & 0x7fffffffu) : ~key;
    float m = __uint_as_float(u);
    float ex = expf(logits[(long long)e * 8 + h] - m);
    logits[(long long)e * 8 + h] = ex;
    atomicAdd(&den[d * 8 + h], ex);
  }
}

__global__ __launch_bounds__(256)
void k_edge_aggr(const int* __restrict__ ei, int E, int TOT,
                 const float* __restrict__ logits, const float* __restrict__ den,
                 const bf16* __restrict__ hh, float* __restrict__ accum) {
  int e = blockIdx.x;
  int s, d;
  if (e < E) { s = ei[e]; d = ei[E + e]; } else { s = d = e - E; }
  #pragma unroll
  for (int half = 0; half < 2; half++) {
    int idx = threadIdx.x + half * 256;
    int h = idx >> 6;
    float alpha = logits[(long long)e * 8 + h] / (den[d * 8 + h] + 1e-16f);
    float v = bf2f(hh[(long long)s * HD + idx]) * alpha;
    atomicAdd(&accum[(long long)d * HD + idx], v);
  }
}

template<int ACT>
__global__ void k_gat_fin(const float* __restrict__ accum, const float* __restrict__ b,
                          bf16* __restrict__ out) {
  int i = blockIdx.x * 256 + threadIdx.x;
  long long n = blockIdx.y;
  float v = accum[n * HD + i] + b[i];
  if (ACT == 2) v = eluf(v);
  out[n * HD + i] = f2bf(v);
}

// post-process for split-K f32 accumulators: bias / act / optional bf16 out
template<int ACT, int BIAS, int TOBF>
__global__ void k_postproc(float* __restrict__ acc, const float* __restrict__ bias,
                           bf16* __restrict__ obf, long long tot, int cols) {
  long long i = (long long)blockIdx.x * 256 + threadIdx.x;
  if (i >= tot) return;
  int c = (int)(i % cols);
  float v = acc[i];
  if (BIAS) v += bias[c];
  if (ACT == 1) v = geluf(v);
  if (TOBF) obf[i] = f2bf(v);
  else acc[i] = v;
}

// row softmax over padded rows: scores bf16 [rows][NPAD] -> attn bf16, scale folded
__global__ __launch_bounds__(256)
void k_softmax_row(const bf16* __restrict__ scores, bf16* __restrict__ attn, int NV) {
  long long row = blockIdx.x;
  const bf16* s = scores + row * NPAD;
  bf16* a = attn + row * NPAD;
  int tid = threadIdx.x;
  __shared__ float red[4];
  float mx = -3.0e38f;
  for (int c = tid; c < NV; c += 256) mx = fmaxf(mx, bf2f(s[c]));
  #pragma unroll
  for (int o = 32; o; o >>= 1) mx = fmaxf(mx, __shfl_down(mx, o, 64));
  if ((tid & 63) == 0) red[tid >> 6] = mx;
  __syncthreads();
  mx = fmaxf(fmaxf(red[0], red[1]), fmaxf(red[2], red[3]));
  const float inv = 0.05590169943749474f;  // 1/sqrt(320)
  float sm = 0.f;
  for (int c = tid; c < NV; c += 256) sm += expf((bf2f(s[c]) - mx) * inv);
  #pragma unroll
  for (int o = 32; o; o >>= 1) sm += __shfl_down(sm, o, 64);
  __syncthreads();
  if ((tid & 63) == 0) red[tid >> 6] = sm;
  __syncthreads();
  sm = red[0] + red[1] + red[2] + red[3];
  float rs = 1.f / sm;
  for (int c = tid; c < NPAD; c += 256) {
    float v = (c < NV) ? expf((bf2f(s[c]) - mx) * inv) * rs : 0.f;
    a[c] = f2bf(v);
  }
}

// LayerNorm(a+b) row of DE, optional bf16 dup
template<int WB>
__global__ __launch_bounds__(256)
void k_ln(const float* __restrict__ a, const float* __restrict__ b,
          const float* __restrict__ g, const float* __restrict__ bt,
          float* __restrict__ out, bf16* __restrict__ obf) {
  long long row = blockIdx.x;
  __shared__ float xs[DE];
  __shared__ float red[4];
  int tid = threadIdx.x;
  float sum = 0.f;
  for (int c = tid; c < DE; c += 256) {
    float v = a[row * DE + c] + b[row * DE + c];
    xs[c] = v; sum += v;
  }
  #pragma unroll
  for (int o = 32; o; o >>= 1) sum += __shfl_down(sum, o, 64);
  if ((tid & 63) == 0) red[tid >> 6] = sum;
  __syncthreads();
  float mean = (red[0] + red[1] + red[2] + red[3]) * (1.f / DE);
  float vs = 0.f;
  for (int c = tid; c < DE; c += 256) { float t = xs[c] - mean; vs += t * t; }
  #pragma unroll
  for (int o = 32; o; o >>= 1) vs += __shfl_down(vs, o, 64);
  __syncthreads();
  if ((tid & 63) == 0) red[tid >> 6] = vs;
  __syncthreads();
  float var = (red[0] + red[1] + red[2] + red[3]) * (1.f / DE);
  float sc = rsqrtf(var + 1e-5f);
  for (int c = tid; c < DE; c += 256) {
    float v = (xs[c] - mean) * sc * g[c] + bt[c];
    out[row * DE + c] = v;
    if (WB) obf[row * DE + c] = f2bf(v);
  }
}

// ---------------- host ----------------
extern "C" void kernel_launch(void* const* d_in, const int* in_sizes, int n_in,
                              void* d_out, int out_size, void* d_ws, size_t ws_size,
                              hipStream_t stream)
{
  const float* x       = (const float*)d_in[0];
  const int*   ei      = (const int*)d_in[1];
  const float* ns_emb  = (const float*)d_in[2];
  const float* gat_w0  = (const float*)d_in[3];
  const float* gat_wr  = (const float*)d_in[4];
  const float* a_src   = (const float*)d_in[5];
  const float* a_dst   = (const float*)d_in[6];
  const float* gat_b   = (const float*)d_in[7];
  const float* proj_w1 = (const float*)d_in[8];
  const float* proj_b1 = (const float*)d_in[9];
  const float* proj_w2 = (const float*)d_in[10];
  const float* proj_b2 = (const float*)d_in[11];
  const float* queries = (const float*)d_in[12];
  const float* wq = (const float*)d_in[13]; const float* bq = (const float*)d_in[14];
  const float* wk = (const float*)d_in[15]; const float* bk = (const float*)d_in[16];
  const float* wv = (const float*)d_in[17]; const float* bv = (const float*)d_in[18];
  const float* wo = (const float*)d_in[19]; const float* bo = (const float*)d_in[20];
  const float* ln1g = (const float*)d_in[21]; const float* ln1b = (const float*)d_in[22];
  const float* fw1 = (const float*)d_in[23]; const float* fb1 = (const float*)d_in[24];
  const float* fw2 = (const float*)d_in[25]; const float* fb2 = (const float*)d_in[26];
  const float* ln2g = (const float*)d_in[27]; const float* ln2b = (const float*)d_in[28];
  float* out = (float*)d_out;

  const int N = in_sizes[0] / DE;   // 30000
  const int E = in_sizes[1] / 2;    // 90000
  const int TOT = E + N;            // 120000
  const int MT = (N + 127) / 128;   // node-dim M tiles

  char* base = (char*)d_ws;
  size_t off = 0;
  auto AL = [&](size_t bytes) -> void* {
    void* p = base + off;
    off += (bytes + 255) & ~(size_t)255;
    return p;
  };
  bf16* wt_g0 = (bf16*)AL((size_t)HD * DE * 2);
  bf16* wt_g1 = (bf16*)AL((size_t)HD * HD * 2);
  bf16* wt_g2 = (bf16*)AL((size_t)HD * HD * 2);
  bf16* wt_p1 = (bf16*)AL((size_t)HD * HD * 2);
  bf16* wt_p2 = (bf16*)AL((size_t)DE * HD * 2);
  bf16* wt_q  = (bf16*)AL((size_t)DE * DE * 2);
  bf16* wt_k  = (bf16*)AL((size_t)DE * DE * 2);
  bf16* wt_v  = (bf16*)AL((size_t)DE * DE * 2);
  bf16* wt_o  = (bf16*)AL((size_t)DE * DE * 2);
  bf16* wt_f1 = (bf16*)AL((size_t)4 * DE * DE * 2);
  bf16* wt_f2 = (bf16*)AL((size_t)4 * DE * DE * 2);
  bf16* big0  = (bf16*)AL((size_t)N * DE * 2);      // h0 -> hD -> scores
  bf16* big1  = (bf16*)AL((size_t)N * DE * 2);      // k  -> attn
  bf16* vT    = (bf16*)AL((size_t)DE * NPAD * 2);
  bf16* hhA   = (bf16*)AL((size_t)N * HD * 2);
  bf16* hB    = (bf16*)AL((size_t)N * HD * 2);
  float* accum  = (float*)AL((size_t)N * HD * 4);
  float* logits = (float*)AL((size_t)TOT * 8 * 4);
  unsigned* mkey = (unsigned*)AL((size_t)N * 8 * 4);
  float* den = (float*)AL((size_t)N * 8 * 4);
  float* es  = (float*)AL((size_t)N * 8 * 4);
  float* edv = (float*)AL((size_t)N * 8 * 4);
  // small f32 pool (zeroed once; targets of split-K atomic GEMMs)
  float* q_f     = (float*)AL((size_t)QNUM * DE * 4);
  float* ctx_f   = (float*)AL((size_t)QNUM * DE * 4);
  float* attnout = (float*)AL((size_t)QNUM * DE * 4);
  float* f1_f    = (float*)AL((size_t)QNUM * 4 * DE * 4);
  float* f2_f    = (float*)AL((size_t)QNUM * DE * 4);
  bf16* qs_bf  = (bf16*)AL((size_t)QNUM * DE * 2);
  bf16* q_bf   = (bf16*)AL((size_t)QNUM * DE * 2);
  bf16* ctx_bf = (bf16*)AL((size_t)QNUM * DE * 2);
  float* attended = (float*)AL((size_t)QNUM * DE * 4);
  bf16* att_bf = (bf16*)AL((size_t)QNUM * DE * 2);
  bf16* f1_bf  = (bf16*)AL((size_t)QNUM * 4 * DE * 2);

  dim3 blk(256);
  dim3 tblk(32, 8);

  // weight convert+transpose to bf16 [out,in]
  k_transpose_bf<<<dim3(HD / 32, DE / 32), tblk, 0, stream>>>(gat_w0, wt_g0, DE, HD);
  k_transpose_bf<<<dim3(HD / 32, HD / 32), tblk, 0, stream>>>(gat_wr, wt_g1, HD, HD);
  k_transpose_bf<<<dim3(HD / 32, HD / 32), tblk, 0, stream>>>(gat_wr + (size_t)HD * HD, wt_g2, HD, HD);
  k_transpose_bf<<<dim3(HD / 32, HD / 32), tblk, 0, stream>>>(proj_w1, wt_p1, HD, HD);
  k_transpose_bf<<<dim3(DE / 32, HD / 32), tblk, 0, stream>>>(proj_w2, wt_p2, HD, DE);
  k_transpose_bf<<<dim3(DE / 32, DE / 32), tblk, 0, stream>>>(wq, wt_q, DE, DE);
  k_transpose_bf<<<dim3(DE / 32, DE / 32), tblk, 0, stream>>>(wk, wt_k, DE, DE);
  k_transpose_bf<<<dim3(DE / 32, DE / 32), tblk, 0, stream>>>(wv, wt_v, DE, DE);
  k_transpose_bf<<<dim3(DE / 32, DE / 32), tblk, 0, stream>>>(wo, wt_o, DE, DE);
  k_transpose_bf<<<dim3(4 * DE / 32, DE / 32), tblk, 0, stream>>>(fw1, wt_f1, DE, 4 * DE);
  k_transpose_bf<<<dim3(DE / 32, 4 * DE / 32), tblk, 0, stream>>>(fw2, wt_f2, 4 * DE, DE);

  // h0 = bf16(x + ns_emb); queries -> bf16; zero small pool
  k_add_emb<<<dim3(DE / 256, N), blk, 0, stream>>>(x, ns_emb, big0);
  k_f2bf<<<dim3((QNUM * DE + 255) / 256), blk, 0, stream>>>(queries, qs_bf, (long long)QNUM * DE);
  {
    long long pool = (long long)QNUM * DE * 4 + (long long)QNUM * 4 * DE;  // q,ctx,attnout,f2 + f1
    k_zero<<<dim3(1024), blk, 0, stream>>>(q_f, pool);
  }

  // ---- GAT layers ----
  const bf16* gw[3] = { wt_g0, wt_g1, wt_g2 };
  const long long zcnt = (long long)N * HD + (long long)TOT * 8 + (long long)N * 16;
  for (int l = 0; l < 3; l++) {
    const bf16* Ain = (l == 0) ? big0 : hB;
    int Kd = (l == 0) ? DE : HD;
    k_gemm_nt<0,0,1,0><<<dim3(4, MT), blk, 0, stream>>>(Ain, gw[l], nullptr, hhA,
        N, HD, Kd, Kd, Kd, HD, 0, 0, 0, 1, Kd);
    k_zero<<<dim3(2048), blk, 0, stream>>>(accum, zcnt);
    k_esed<<<dim3(N), dim3(512), 0, stream>>>(hhA, a_src + l * HD, a_dst + l * HD, es, edv);
    k_edge_logits<<<dim3((TOT + 255) / 256), blk, 0, stream>>>(ei, E, TOT, es, edv, logits, mkey);
    k_edge_exp<<<dim3((TOT + 255) / 256), blk, 0, stream>>>(ei, E, TOT, mkey, logits, den);
    k_edge_aggr<<<dim3(TOT), blk, 0, stream>>>(ei, E, TOT, logits, den, hhA, accum);
    if (l < 2) k_gat_fin<2><<<dim3(2, N), blk, 0, stream>>>(accum, gat_b + l * HD, hB);
    else       k_gat_fin<0><<<dim3(2, N), blk, 0, stream>>>(accum, gat_b + l * HD, hB);
  }

  // ---- projection: p1 = gelu(h@W1+b1); hD = p1@W2+b2 ----
  k_gemm_nt<1,1,1,0><<<dim3(4, MT), blk, 0, stream>>>(hB, wt_p1, proj_b1, hhA,
      N, HD, HD, HD, HD, HD, 0, 0, 0, 1, HD);
  k_gemm_nt<0,1,1,0><<<dim3(20, MT), blk, 0, stream>>>(hhA, wt_p2, proj_b2, big0,
      N, DE, HD, HD, HD, DE, 0, 0, 0, 1, HD);

  // ---- q (split-K 8), k, v(transposed out) ----
  k_gemm_nt<0,0,2,0><<<dim3(20, 2, 8), blk, 0, stream>>>(qs_bf, wt_q, nullptr, q_f,
      QNUM, DE, DE, DE, DE, DE, 0, 0, 0, 8, 320);
  k_postproc<0,1,1><<<dim3((QNUM * DE + 255) / 256), blk, 0, stream>>>(q_f, bq, q_bf,
      (long long)QNUM * DE, DE);
  k_gemm_nt<0,1,1,0><<<dim3(20, MT), blk, 0, stream>>>(big0, wt_k, bk, big1,
      N, DE, DE, DE, DE, DE, 0, 0, 0, 1, DE);
  k_gemm_nt<0,1,1,1><<<dim3(20, MT), blk, 0, stream>>>(big0, wt_v, bv, vT,
      N, DE, DE, DE, DE, NPAD, 0, 0, 0, 1, DE);

  // ---- scores (batched over 8 heads), softmax, ctx (split-K 16) ----
  k_gemm_nt<0,0,1,0><<<dim3(MT, 2, 8), blk, 0, stream>>>(q_bf, big1, nullptr, big0,
      QNUM, N, ADHD, DE, DE, NPAD, 320, 320, (long long)QNUM * NPAD, 1, ADHD);
  k_softmax_row<<<dim3(8 * QNUM), blk, 0, stream>>>(big0, big1, N);
  k_gemm_nt<0,0,2,0><<<dim3(3, 2, 8 * 16), blk, 0, stream>>>(big1, vT, nullptr, ctx_f,
      QNUM, ADHD, NPAD, NPAD, NPAD, DE, (long long)QNUM * NPAD, (long long)ADHD * NPAD, 320, 16, 1888);
  k_postproc<0,0,1><<<dim3((QNUM * DE + 255) / 256), blk, 0, stream>>>(ctx_f, nullptr, ctx_bf,
      (long long)QNUM * DE, DE);

  // ---- output projection + LN1 ----
  k_gemm_nt<0,0,2,0><<<dim3(20, 2, 8), blk, 0, stream>>>(ctx_bf, wt_o, nullptr, attnout,
      QNUM, DE, DE, DE, DE, DE, 0, 0, 0, 8, 320);
  k_postproc<0,1,0><<<dim3((QNUM * DE + 255) / 256), blk, 0, stream>>>(attnout, bo, nullptr,
      (long long)QNUM * DE, DE);
  k_ln<1><<<dim3(QNUM), blk, 0, stream>>>(queries, attnout, ln1g, ln1b, attended, att_bf);

  // ---- FFN + LN2 ----
  k_gemm_nt<0,0,2,0><<<dim3(80, 2, 4), blk, 0, stream>>>(att_bf, wt_f1, nullptr, f1_f,
      QNUM, 4 * DE, DE, DE, DE, 4 * DE, 0, 0, 0, 4, 640);
  k_postproc<1,1,1><<<dim3((QNUM * 4 * DE + 255) / 256), blk, 0, stream>>>(f1_f, fb1, f1_bf,
      (long long)QNUM * 4 * DE, 4 * DE);
  k_gemm_nt<0,0,2,0><<<dim3(20, 2, 8), blk, 0, stream>>>(f1_bf, wt_f2, nullptr, f2_f,
      QNUM, DE, 4 * DE, 4 * DE, 4 * DE, DE, 0, 0, 0, 8, 1280);
  k_postproc<0,1,0><<<dim3((QNUM * DE + 255) / 256), blk, 0, stream>>>(f2_f, fb2, nullptr,
      (long long)QNUM * DE, DE);
  k_ln<0><<<dim3(QNUM), blk, 0, stream>>>(attended, f2_f, ln2g, ln2b, out, nullptr);
}

// Round 2
// 3417.474 us; speedup vs baseline: 1.0531x; 1.0531x over previous
//
#include <hip/hip_runtime.h>
#include <hip/hip_bf16.h>
#include <cmath>

typedef __hip_bfloat16 bf16;
typedef __attribute__((ext_vector_type(8))) short short8;
typedef __attribute__((ext_vector_type(4))) float f32x4;
typedef __attribute__((address_space(1))) void as1_void;
typedef __attribute__((address_space(3))) void as3_void;

#define DE   2560
#define HD   512
#define NPAD 30016
#define QNUM 200
#define ADHD 320

static __device__ __forceinline__ float bf2f(bf16 v){ return __bfloat162float(v); }
static __device__ __forceinline__ bf16  f2bf(float v){ return __float2bfloat16(v); }
static __device__ __forceinline__ float geluf(float x){ return 0.5f*x*(1.0f+erff(x*0.70710678118654752440f)); }
static __device__ __forceinline__ float eluf(float x){ return x>0.f ? x : expm1f(x); }

static __device__ __forceinline__ void gload16(const void* g, void* l){
  __builtin_amdgcn_global_load_lds((as1_void*)g, (as3_void*)l, 16, 0, 0);
}

// ---------------- generic bf16 NT GEMM: C[M,N] = A[M,K] * B[N,K]^T ----------------
// 128x128 tile, BK=32, 4 waves, 3-deep LDS buffers with counted-vmcnt prefetch
// (stage t+2 while computing t; loads stay in flight across raw s_barrier).
// LDS chunk swizzle: chunk-col ^= (row>>1)&3 applied on BOTH global source and
// ds_read (rule 21: both-sides-or-neither) -> 8-way bank conflict becomes 2-way.
// ACT: 0 none, 1 gelu, 2 elu. OBF: 0 f32 store, 1 bf16 store, 2 f32 atomicAdd.
// TROUT: store C[col*ldc+row].
template<int ACT, int BIAS, int OBF, int TROUT>
__global__ __launch_bounds__(256)
void k_gemm_nt(const bf16* __restrict__ A, const bf16* __restrict__ B,
               const float* __restrict__ bias, void* __restrict__ Cv,
               int M, int N, int K, int lda, int ldb, int ldc,
               long long sA, long long sB, long long sC, int nsplit, int ks)
{
  __shared__ __align__(16) bf16 As[3][128*32];
  __shared__ __align__(16) bf16 Bs[3][128*32];
  const int zb = blockIdx.z;
  const int b  = zb / nsplit;
  const int sl = zb - b*nsplit;
  const int kbeg = sl * ks;
  int kend = kbeg + ks; if (kend > K) kend = K;
  const int nt = (kend > kbeg) ? (kend - kbeg + 31) / 32 : 0;

  const bf16* Ab = A + (long long)b * sA;
  const bf16* Bb = B + (long long)b * sB;
  const long long cbase = (long long)b * sC;

  // ---- block swizzle: XCD-bijective chunking, then GROUP_M supertile ----
  const int NTt = gridDim.x, MTt = gridDim.y;
  const int nwg = NTt * MTt;
  int orig = blockIdx.y * NTt + blockIdx.x;
  {
    const int q8 = nwg >> 3, r8 = nwg & 7;
    const int xcd = orig & 7, idx = orig >> 3;
    orig = (xcd < r8 ? xcd * (q8 + 1) : r8 * (q8 + 1) + (xcd - r8) * q8) + idx;
  }
  const int GM = 8;
  const int per_g = GM * NTt;
  const int g = orig / per_g, rem = orig - g * per_g;
  int gsz = MTt - g * GM; if (gsz > GM) gsz = GM;
  const int mi = g * GM + rem % gsz;
  const int ni = rem / gsz;

  const int m0 = mi * 128, n0 = ni * 128;
  const int tid = threadIdx.x, lane = tid & 63, wave = tid >> 6;
  const int wm = (wave >> 1) * 64, wn = (wave & 1) * 64;
  const int fr = lane & 15, fg = lane >> 4;
  const int fgs = fg ^ ((fr >> 1) & 3);     // swizzled chunk for frag reads

  f32x4 acc[4][4];
  #pragma unroll
  for (int i = 0; i < 4; i++)
    #pragma unroll
    for (int j = 0; j < 4; j++) acc[i][j] = (f32x4){0.f, 0.f, 0.f, 0.f};

  // staging geometry: per wave 2 chunks-of-64 for A and for B (chunk = 16B)
  const int c0 = wave * 128 + lane;
  const int c1 = c0 + 64;
  const int rA0 = c0 >> 2, rA1 = c1 >> 2;
  const int cc0 = ((c0 & 3) ^ ((rA0 >> 1) & 3)) * 8;   // swizzled source col
  const int cc1 = ((c1 & 3) ^ ((rA1 >> 1) & 3)) * 8;
  int gra0 = m0 + rA0; if (gra0 >= M) gra0 = M - 1;
  int gra1 = m0 + rA1; if (gra1 >= M) gra1 = M - 1;
  int grb0 = n0 + rA0; if (grb0 >= N) grb0 = N - 1;
  int grb1 = n0 + rA1; if (grb1 >= N) grb1 = N - 1;
  const bf16* pa0 = Ab + (long long)gra0 * lda + cc0;
  const bf16* pa1 = Ab + (long long)gra1 * lda + cc1;
  const bf16* pb0 = Bb + (long long)grb0 * ldb + cc0;
  const bf16* pb1 = Bb + (long long)grb1 * ldb + cc1;

  char* lA = (char*)&As[0][0] + wave * 2048;
  char* lB = (char*)&Bs[0][0] + wave * 2048;

  #define STAGE(buf, kk) do {                       \
    char* a_ = lA + (buf) * 8192;                   \
    char* b_ = lB + (buf) * 8192;                   \
    gload16(pa0 + (kk), a_);                        \
    gload16(pa1 + (kk), a_ + 1024);                 \
    gload16(pb0 + (kk), b_);                        \
    gload16(pb1 + (kk), b_ + 1024);                 \
  } while (0)

  if (nt > 0) STAGE(0, kbeg);
  if (nt > 1) STAGE(1, kbeg + 32);

  int cur = 0;
  for (int t = 0; t < nt; t++) {
    if (t + 2 < nt) {
      int n2 = cur + 2; if (n2 >= 3) n2 -= 3;
      STAGE(n2, kbeg + (t + 2) * 32);
      asm volatile("s_waitcnt vmcnt(8)" ::: "memory");
    } else if (t + 1 < nt) {
      asm volatile("s_waitcnt vmcnt(4)" ::: "memory");
    } else {
      asm volatile("s_waitcnt vmcnt(0)" ::: "memory");
    }
    __builtin_amdgcn_s_barrier();

    const bf16* Asb = (const bf16*)((const char*)&As[0][0] + cur * 8192);
    const bf16* Bsb = (const bf16*)((const char*)&Bs[0][0] + cur * 8192);
    short8 af[4], bfv[4];
    #pragma unroll
    for (int i = 0; i < 4; i++) {
      af[i]  = *(const short8*)(Asb + (wm + i * 16 + fr) * 32 + fgs * 8);
      bfv[i] = *(const short8*)(Bsb + (wn + i * 16 + fr) * 32 + fgs * 8);
    }
    #pragma unroll
    for (int i = 0; i < 4; i++)
      #pragma unroll
      for (int j = 0; j < 4; j++)
        acc[i][j] = __builtin_amdgcn_mfma_f32_16x16x32_bf16(af[i], bfv[j], acc[i][j], 0, 0, 0);

    asm volatile("s_waitcnt lgkmcnt(0)" ::: "memory");
    __builtin_amdgcn_s_barrier();
    cur = cur + 1; if (cur >= 3) cur = 0;
  }
  #undef STAGE

  #pragma unroll
  for (int i = 0; i < 4; i++) {
    const int r0 = m0 + wm + i * 16 + fg * 4;
    #pragma unroll
    for (int j = 0; j < 4; j++) {
      const int col = n0 + wn + j * 16 + fr;
      if (col >= N) continue;
      float bv = 0.f;
      if (BIAS) bv = bias[col];
      #pragma unroll
      for (int r = 0; r < 4; r++) {
        const int row = r0 + r;
        if (row >= M) continue;
        float v = acc[i][j][r] + bv;
        if (ACT == 1) v = geluf(v);
        else if (ACT == 2) v = eluf(v);
        long long off;
        if (TROUT) off = cbase + (long long)col * ldc + row;
        else       off = cbase + (long long)row * ldc + col;
        if (OBF == 1)      ((bf16*)Cv)[off] = f2bf(v);
        else if (OBF == 2) atomicAdd(&((float*)Cv)[off], v);
        else               ((float*)Cv)[off] = v;
      }
    }
  }
}

// ---------------- small utility kernels ----------------
__global__ void k_zero(float* p, long long n) {
  long long i = (long long)blockIdx.x * blockDim.x + threadIdx.x;
  long long st = (long long)gridDim.x * blockDim.x;
  for (; i < n; i += st) p[i] = 0.f;
}

__global__ void k_f2bf(const float* __restrict__ in, bf16* __restrict__ out, long long n) {
  long long i = (long long)blockIdx.x * 256 + threadIdx.x;
  if (i < n) out[i] = f2bf(in[i]);
}

__global__ void k_add_emb(const float* __restrict__ x, const float* __restrict__ ns,
                          bf16* __restrict__ h0) {
  int d = blockIdx.x * 256 + threadIdx.x;
  long long n = blockIdx.y;
  h0[n * DE + d] = f2bf(x[n * DE + d] + ns[d]);
}

// transpose f32 [R,C] -> bf16 [C,R]; R,C multiples of 32
__global__ void k_transpose_bf(const float* __restrict__ W, bf16* __restrict__ Wt, int R, int C) {
  __shared__ float t[32][33];
  int c0 = blockIdx.x * 32, r0 = blockIdx.y * 32;
  int x = threadIdx.x, y = threadIdx.y;
  #pragma unroll
  for (int j = 0; j < 32; j += 8)
    t[y + j][x] = W[(long long)(r0 + y + j) * C + c0 + x];
  __syncthreads();
  #pragma unroll
  for (int j = 0; j < 32; j += 8)
    Wt[(long long)(c0 + y + j) * R + r0 + x] = f2bf(t[x][y + j]);
}

// es/ed per node: block = 512 threads, wave w = head
__global__ __launch_bounds__(512)
void k_esed(const bf16* __restrict__ hh, const float* __restrict__ asrc,
            const float* __restrict__ adst, float* __restrict__ es, float* __restrict__ ed) {
  int n = blockIdx.x;
  int h = threadIdx.x >> 6;
  int c = threadIdx.x & 63;
  float v = bf2f(hh[(long long)n * HD + h * 64 + c]);
  float s = v * asrc[h * 64 + c];
  float d = v * adst[h * 64 + c];
  #pragma unroll
  for (int o = 32; o; o >>= 1) { s += __shfl_down(s, o, 64); d += __shfl_down(d, o, 64); }
  if (c == 0) { es[n * 8 + h] = s; ed[n * 8 + h] = d; }
}

__global__ void k_edge_logits(const int* __restrict__ ei, int E, int TOT,
                              const float* __restrict__ es, const float* __restrict__ ed,
                              float* __restrict__ logits, unsigned* __restrict__ mkey) {
  int e = blockIdx.x * 256 + threadIdx.x;
  if (e >= TOT) return;
  int s, d;
  if (e < E) { s = ei[e]; d = ei[E + e]; } else { s = d = e - E; }
  #pragma unroll
  for (int h = 0; h < 8; h++) {
    float l = es[s * 8 + h] + ed[d * 8 + h];
    l = l > 0.f ? l : 0.2f * l;
    logits[(long long)e * 8 + h] = l;
    unsigned u = __float_as_uint(l);
    unsigned key = (u & 0x80000000u) ? ~u : (u | 0x80000000u);
    atomicMax(&mkey[d * 8 + h], key);
  }
}

__global__ void k_edge_exp(const int* __restrict__ ei, int E, int TOT,
                           const unsigned* __restrict__ mkey, float* __restrict__ logits,
                           float* __restrict__ den) {
  int e = blockIdx.x * 256 + threadIdx.x;
  if (e >= TOT) return;
  int d = (e < E) ? ei[E + e] : (e - E);
  #pragma unroll
  for (int h = 0; h < 8; h++) {
    unsigned key = mkey[d * 8 + h];
    unsigned u = (key & 0x80000000u) ? (key & 0x7fffffffu) : ~key;
    float m = __uint_as_float(u);
    float ex = expf(logits[(long long)e * 8 + h] - m);
    logits[(long long)e * 8 + h] = ex;
    atomicAdd(&den[d * 8 + h], ex);
  }
}

// 4 edges per block
__global__ __launch_bounds__(256)
void k_edge_aggr(const int* __restrict__ ei, int E, int TOT,
                 const float* __restrict__ logits, const float* __restrict__ den,
                 const bf16* __restrict__ hh, float* __restrict__ accum) {
  int base = blockIdx.x * 4;
  for (int u = 0; u < 4; u++) {
    int e = base + u;
    if (e >= TOT) break;
    int s, d;
    if (e < E) { s = ei[e]; d = ei[E + e]; } else { s = d = e - E; }
    #pragma unroll
    for (int half = 0; half < 2; half++) {
      int idx = threadIdx.x + half * 256;
      int h = idx >> 6;
      float alpha = logits[(long long)e * 8 + h] / (den[d * 8 + h] + 1e-16f);
      float v = bf2f(hh[(long long)s * HD + idx]) * alpha;
      atomicAdd(&accum[(long long)d * HD + idx], v);
    }
  }
}

template<int ACT>
__global__ void k_gat_fin(const float* __restrict__ accum, const float* __restrict__ b,
                          bf16* __restrict__ out) {
  int i = blockIdx.x * 256 + threadIdx.x;
  long long n = blockIdx.y;
  float v = accum[n * HD + i] + b[i];
  if (ACT == 2) v = eluf(v);
  out[n * HD + i] = f2bf(v);
}

// post-process for split-K f32 accumulators: bias / act / optional bf16 out
template<int ACT, int BIAS, int TOBF>
__global__ void k_postproc(float* __restrict__ acc, const float* __restrict__ bias,
                           bf16* __restrict__ obf, long long tot, int cols) {
  long long i = (long long)blockIdx.x * 256 + threadIdx.x;
  if (i >= tot) return;
  int c = (int)(i % cols);
  float v = acc[i];
  if (BIAS) v += bias[c];
  if (ACT == 1) v = geluf(v);
  if (TOBF) obf[i] = f2bf(v);
  else acc[i] = v;
}

// row softmax over padded rows: scores bf16 [rows][NPAD] -> attn bf16, scale folded
__global__ __launch_bounds__(256)
void k_softmax_row(const bf16* __restrict__ scores, bf16* __restrict__ attn, int NV) {
  long long row = blockIdx.x;
  const bf16* s = scores + row * NPAD;
  bf16* a = attn + row * NPAD;
  int tid = threadIdx.x;
  __shared__ float red[4];
  float mx = -3.0e38f;
  for (int c = tid; c < NV; c += 256) mx = fmaxf(mx, bf2f(s[c]));
  #pragma unroll
  for (int o = 32; o; o >>= 1) mx = fmaxf(mx, __shfl_down(mx, o, 64));
  if ((tid & 63) == 0) red[tid >> 6] = mx;
  __syncthreads();
  mx = fmaxf(fmaxf(red[0], red[1]), fmaxf(red[2], red[3]));
  const float inv = 0.05590169943749474f;  // 1/sqrt(320)
  float sm = 0.f;
  for (int c = tid; c < NV; c += 256) sm += expf((bf2f(s[c]) - mx) * inv);
  #pragma unroll
  for (int o = 32; o; o >>= 1) sm += __shfl_down(sm, o, 64);
  __syncthreads();
  if ((tid & 63) == 0) red[tid >> 6] = sm;
  __syncthreads();
  sm = red[0] + red[1] + red[2] + red[3];
  float rs = 1.f / sm;
  for (int c = tid; c < NPAD; c += 256) {
    float v = (c < NV) ? expf((bf2f(s[c]) - mx) * inv) * rs : 0.f;
    a[c] = f2bf(v);
  }
}

// LayerNorm(a+b) row of DE, optional bf16 dup
template<int WB>
__global__ __launch_bounds__(256)
void k_ln(const float* __restrict__ a, const float* __restrict__ b,
          const float* __restrict__ g, const float* __restrict__ bt,
          float* __restrict__ out, bf16* __restrict__ obf) {
  long long row = blockIdx.x;
  __shared__ float xs[DE];
  __shared__ float red[4];
  int tid = threadIdx.x;
  float sum = 0.f;
  for (int c = tid; c < DE; c += 256) {
    float v = a[row * DE + c] + b[row * DE + c];
    xs[c] = v; sum += v;
  }
  #pragma unroll
  for (int o = 32; o; o >>= 1) sum += __shfl_down(sum, o, 64);
  if ((tid & 63) == 0) red[tid >> 6] = sum;
  __syncthreads();
  float mean = (red[0] + red[1] + red[2] + red[3]) * (1.f / DE);
  float vs = 0.f;
  for (int c = tid; c < DE; c += 256) { float t = xs[c] - mean; vs += t * t; }
  #pragma unroll
  for (int o = 32; o; o >>= 1) vs += __shfl_down(vs, o, 64);
  __syncthreads();
  if ((tid & 63) == 0) red[tid >> 6] = vs;
  __syncthreads();
  float var = (red[0] + red[1] + red[2] + red[3]) * (1.f / DE);
  float sc = rsqrtf(var + 1e-5f);
  for (int c = tid; c < DE; c += 256) {
    float v = (xs[c] - mean) * sc * g[c] + bt[c];
    out[row * DE + c] = v;
    if (WB) obf[row * DE + c] = f2bf(v);
  }
}

// ---------------- host ----------------
extern "C" void kernel_launch(void* const* d_in, const int* in_sizes, int n_in,
                              void* d_out, int out_size, void* d_ws, size_t ws_size,
                              hipStream_t stream)
{
  const float* x       = (const float*)d_in[0];
  const int*   ei      = (const int*)d_in[1];
  const float* ns_emb  = (const float*)d_in[2];
  const float* gat_w0  = (const float*)d_in[3];
  const float* gat_wr  = (const float*)d_in[4];
  const float* a_src   = (const float*)d_in[5];
  const float* a_dst   = (const float*)d_in[6];
  const float* gat_b   = (const float*)d_in[7];
  const float* proj_w1 = (const float*)d_in[8];
  const float* proj_b1 = (const float*)d_in[9];
  const float* proj_w2 = (const float*)d_in[10];
  const float* proj_b2 = (const float*)d_in[11];
  const float* queries = (const float*)d_in[12];
  const float* wq = (const float*)d_in[13]; const float* bq = (const float*)d_in[14];
  const float* wk = (const float*)d_in[15]; const float* bk = (const float*)d_in[16];
  const float* wv = (const float*)d_in[17]; const float* bv = (const float*)d_in[18];
  const float* wo = (const float*)d_in[19]; const float* bo = (const float*)d_in[20];
  const float* ln1g = (const float*)d_in[21]; const float* ln1b = (const float*)d_in[22];
  const float* fw1 = (const float*)d_in[23]; const float* fb1 = (const float*)d_in[24];
  const float* fw2 = (const float*)d_in[25]; const float* fb2 = (const float*)d_in[26];
  const float* ln2g = (const float*)d_in[27]; const float* ln2b = (const float*)d_in[28];
  float* out = (float*)d_out;

  const int N = in_sizes[0] / DE;   // 30000
  const int E = in_sizes[1] / 2;    // 90000
  const int TOT = E + N;            // 120000
  const int MT = (N + 127) / 128;   // node-dim M tiles (235)

  char* base = (char*)d_ws;
  size_t off = 0;
  auto AL = [&](size_t bytes) -> void* {
    void* p = base + off;
    off += (bytes + 255) & ~(size_t)255;
    return p;
  };
  bf16* wt_g0 = (bf16*)AL((size_t)HD * DE * 2);
  bf16* wt_g1 = (bf16*)AL((size_t)HD * HD * 2);
  bf16* wt_g2 = (bf16*)AL((size_t)HD * HD * 2);
  bf16* wt_p1 = (bf16*)AL((size_t)HD * HD * 2);
  bf16* wt_p2 = (bf16*)AL((size_t)DE * HD * 2);
  bf16* wt_q  = (bf16*)AL((size_t)DE * DE * 2);
  bf16* wt_k  = (bf16*)AL((size_t)DE * DE * 2);
  bf16* wt_v  = (bf16*)AL((size_t)DE * DE * 2);
  bf16* wt_o  = (bf16*)AL((size_t)DE * DE * 2);
  bf16* wt_f1 = (bf16*)AL((size_t)4 * DE * DE * 2);
  bf16* wt_f2 = (bf16*)AL((size_t)4 * DE * DE * 2);
  bf16* big0  = (bf16*)AL((size_t)N * DE * 2);      // h0 -> hD -> scores
  bf16* big1  = (bf16*)AL((size_t)N * DE * 2);      // k  -> attn
  bf16* vT    = (bf16*)AL((size_t)DE * NPAD * 2);
  bf16* hhA   = (bf16*)AL((size_t)N * HD * 2);
  bf16* hB    = (bf16*)AL((size_t)N * HD * 2);
  float* accum  = (float*)AL((size_t)N * HD * 4);
  float* logits = (float*)AL((size_t)TOT * 8 * 4);
  unsigned* mkey = (unsigned*)AL((size_t)N * 8 * 4);
  float* den = (float*)AL((size_t)N * 8 * 4);
  float* es  = (float*)AL((size_t)N * 8 * 4);
  float* edv = (float*)AL((size_t)N * 8 * 4);
  // small f32 pool (zeroed once; targets of split-K atomic GEMMs)
  float* q_f     = (float*)AL((size_t)QNUM * DE * 4);
  float* ctx_f   = (float*)AL((size_t)QNUM * DE * 4);
  float* attnout = (float*)AL((size_t)QNUM * DE * 4);
  float* f1_f    = (float*)AL((size_t)QNUM * 4 * DE * 4);
  float* f2_f    = (float*)AL((size_t)QNUM * DE * 4);
  bf16* qs_bf  = (bf16*)AL((size_t)QNUM * DE * 2);
  bf16* q_bf   = (bf16*)AL((size_t)QNUM * DE * 2);
  bf16* ctx_bf = (bf16*)AL((size_t)QNUM * DE * 2);
  float* attended = (float*)AL((size_t)QNUM * DE * 4);
  bf16* att_bf = (bf16*)AL((size_t)QNUM * DE * 2);
  bf16* f1_bf  = (bf16*)AL((size_t)QNUM * 4 * DE * 2);

  dim3 blk(256);
  dim3 tblk(32, 8);

  // weight convert+transpose to bf16 [out,in]
  k_transpose_bf<<<dim3(HD / 32, DE / 32), tblk, 0, stream>>>(gat_w0, wt_g0, DE, HD);
  k_transpose_bf<<<dim3(HD / 32, HD / 32), tblk, 0, stream>>>(gat_wr, wt_g1, HD, HD);
  k_transpose_bf<<<dim3(HD / 32, HD / 32), tblk, 0, stream>>>(gat_wr + (size_t)HD * HD, wt_g2, HD, HD);
  k_transpose_bf<<<dim3(HD / 32, HD / 32), tblk, 0, stream>>>(proj_w1, wt_p1, HD, HD);
  k_transpose_bf<<<dim3(DE / 32, HD / 32), tblk, 0, stream>>>(proj_w2, wt_p2, HD, DE);
  k_transpose_bf<<<dim3(DE / 32, DE / 32), tblk, 0, stream>>>(wq, wt_q, DE, DE);
  k_transpose_bf<<<dim3(DE / 32, DE / 32), tblk, 0, stream>>>(wk, wt_k, DE, DE);
  k_transpose_bf<<<dim3(DE / 32, DE / 32), tblk, 0, stream>>>(wv, wt_v, DE, DE);
  k_transpose_bf<<<dim3(DE / 32, DE / 32), tblk, 0, stream>>>(wo, wt_o, DE, DE);
  k_transpose_bf<<<dim3(4 * DE / 32, DE / 32), tblk, 0, stream>>>(fw1, wt_f1, DE, 4 * DE);
  k_transpose_bf<<<dim3(DE / 32, 4 * DE / 32), tblk, 0, stream>>>(fw2, wt_f2, 4 * DE, DE);

  // h0 = bf16(x + ns_emb); queries -> bf16; zero small pool
  k_add_emb<<<dim3(DE / 256, N), blk, 0, stream>>>(x, ns_emb, big0);
  k_f2bf<<<dim3((QNUM * DE + 255) / 256), blk, 0, stream>>>(queries, qs_bf, (long long)QNUM * DE);
  {
    long long pool = (long long)QNUM * DE * 4 + (long long)QNUM * 4 * DE;  // q,ctx,attnout,f2 + f1
    k_zero<<<dim3(1024), blk, 0, stream>>>(q_f, pool);
  }

  // ---- GAT layers ----
  const bf16* gw[3] = { wt_g0, wt_g1, wt_g2 };
  const long long zcnt = (long long)N * HD + (long long)TOT * 8 + (long long)N * 16;
  for (int l = 0; l < 3; l++) {
    const bf16* Ain = (l == 0) ? big0 : hB;
    int Kd = (l == 0) ? DE : HD;
    k_gemm_nt<0,0,1,0><<<dim3(4, MT), blk, 0, stream>>>(Ain, gw[l], nullptr, hhA,
        N, HD, Kd, Kd, Kd, HD, 0, 0, 0, 1, Kd);
    k_zero<<<dim3(2048), blk, 0, stream>>>(accum, zcnt);
    k_esed<<<dim3(N), dim3(512), 0, stream>>>(hhA, a_src + l * HD, a_dst + l * HD, es, edv);
    k_edge_logits<<<dim3((TOT + 255) / 256), blk, 0, stream>>>(ei, E, TOT, es, edv, logits, mkey);
    k_edge_exp<<<dim3((TOT + 255) / 256), blk, 0, stream>>>(ei, E, TOT, mkey, logits, den);
    k_edge_aggr<<<dim3((TOT + 3) / 4), blk, 0, stream>>>(ei, E, TOT, logits, den, hhA, accum);
    if (l < 2) k_gat_fin<2><<<dim3(2, N), blk, 0, stream>>>(accum, gat_b + l * HD, hB);
    else       k_gat_fin<0><<<dim3(2, N), blk, 0, stream>>>(accum, gat_b + l * HD, hB);
  }

  // ---- projection: p1 = gelu(h@W1+b1); hD = p1@W2+b2 ----
  k_gemm_nt<1,1,1,0><<<dim3(4, MT), blk, 0, stream>>>(hB, wt_p1, proj_b1, hhA,
      N, HD, HD, HD, HD, HD, 0, 0, 0, 1, HD);
  k_gemm_nt<0,1,1,0><<<dim3(20, MT), blk, 0, stream>>>(hhA, wt_p2, proj_b2, big0,
      N, DE, HD, HD, HD, DE, 0, 0, 0, 1, HD);

  // ---- q (split-K 8), k, v(transposed out) ----
  k_gemm_nt<0,0,2,0><<<dim3(20, 2, 8), blk, 0, stream>>>(qs_bf, wt_q, nullptr, q_f,
      QNUM, DE, DE, DE, DE, DE, 0, 0, 0, 8, 320);
  k_postproc<0,1,1><<<dim3((QNUM * DE + 255) / 256), blk, 0, stream>>>(q_f, bq, q_bf,
      (long long)QNUM * DE, DE);
  k_gemm_nt<0,1,1,0><<<dim3(20, MT), blk, 0, stream>>>(big0, wt_k, bk, big1,
      N, DE, DE, DE, DE, DE, 0, 0, 0, 1, DE);
  k_gemm_nt<0,1,1,1><<<dim3(20, MT), blk, 0, stream>>>(big0, wt_v, bv, vT,
      N, DE, DE, DE, DE, NPAD, 0, 0, 0, 1, DE);

  // ---- scores (batched over 8 heads), softmax, ctx (split-K 32) ----
  k_gemm_nt<0,0,1,0><<<dim3(MT, 2, 8), blk, 0, stream>>>(q_bf, big1, nullptr, big0,
      QNUM, N, ADHD, DE, DE, NPAD, 320, 320, (long long)QNUM * NPAD, 1, ADHD);
  k_softmax_row<<<dim3(8 * QNUM), blk, 0, stream>>>(big0, big1, N);
  k_gemm_nt<0,0,2,0><<<dim3(3, 2, 8 * 32), blk, 0, stream>>>(big1, vT, nullptr, ctx_f,
      QNUM, ADHD, NPAD, NPAD, NPAD, DE, (long long)QNUM * NPAD, (long long)ADHD * NPAD, 320, 32, 960);
  k_postproc<0,0,1><<<dim3((QNUM * DE + 255) / 256), blk, 0, stream>>>(ctx_f, nullptr, ctx_bf,
      (long long)QNUM * DE, DE);

  // ---- output projection + LN1 ----
  k_gemm_nt<0,0,2,0><<<dim3(20, 2, 8), blk, 0, stream>>>(ctx_bf, wt_o, nullptr, attnout,
      QNUM, DE, DE, DE, DE, DE, 0, 0, 0, 8, 320);
  k_postproc<0,1,0><<<dim3((QNUM * DE + 255) / 256), blk, 0, stream>>>(attnout, bo, nullptr,
      (long long)QNUM * DE, DE);
  k_ln<1><<<dim3(QNUM), blk, 0, stream>>>(queries, attnout, ln1g, ln1b, attended, att_bf);

  // ---- FFN + LN2 ----
  k_gemm_nt<0,0,2,0><<<dim3(80, 2, 4), blk, 0, stream>>>(att_bf, wt_f1, nullptr, f1_f,
      QNUM, 4 * DE, DE, DE, DE, 4 * DE, 0, 0, 0, 4, 640);
  k_postproc<1,1,1><<<dim3((QNUM * 4 * DE + 255) / 256), blk, 0, stream>>>(f1_f, fb1, f1_bf,
      (long long)QNUM * 4 * DE, 4 * DE);
  k_gemm_nt<0,0,2,0><<<dim3(20, 2, 8), blk, 0, stream>>>(f1_bf, wt_f2, nullptr, f2_f,
      QNUM, DE, 4 * DE, 4 * DE, 4 * DE, DE, 0, 0, 0, 8, 1280);
  k_postproc<0,1,0><<<dim3((QNUM * DE + 255) / 256), blk, 0, stream>>>(f2_f, fb2, nullptr,
      (long long)QNUM * DE, DE);
  k_ln<0><<<dim3(QNUM), blk, 0, stream>>>(attended, f2_f, ln2g, ln2b, out, nullptr);
}

// Round 3
// 2868.872 us; speedup vs baseline: 1.2545x; 1.1912x over previous
//
#include <hip/hip_runtime.h>
#include <hip/hip_bf16.h>
#include <cmath>

typedef __hip_bfloat16 bf16;
typedef __attribute__((ext_vector_type(8))) short short8;
typedef __attribute__((ext_vector_type(4))) short short4_t;
typedef __attribute__((ext_vector_type(4))) float f32x4;
typedef __attribute__((address_space(1))) void as1_void;
typedef __attribute__((address_space(3))) void as3_void;

#define DE   2560
#define HD   512
#define NPAD 30016
#define QNUM 200
#define ADHD 320

static __device__ __forceinline__ float bf2f(bf16 v){ return __bfloat162float(v); }
static __device__ __forceinline__ bf16  f2bf(float v){ return __float2bfloat16(v); }
static __device__ __forceinline__ short bfbits(float f){ bf16 b = f2bf(f); return *reinterpret_cast<short*>(&b); }
static __device__ __forceinline__ float geluf(float x){ return 0.5f*x*(1.0f+erff(x*0.70710678118654752440f)); }
static __device__ __forceinline__ float eluf(float x){ return x>0.f ? x : expm1f(x); }

static __device__ __forceinline__ void gload16(const void* g, void* l){
  __builtin_amdgcn_global_load_lds((as1_void*)g, (as3_void*)l, 16, 0, 0);
}

// =================== 256x256 8-phase bf16 NT GEMM ===================
// C[M,N](bf16) = act(A[M,K] * B[N,K]^T + bias). BK=64, 512 thr (8 waves 2Mx4N),
// 128KB LDS dbuf. 4 phases/K-tile: counted vmcnt (never 0 mid-loop), one
// granule (half-operand, 2 gload_lds/thread) staged per phase for tile t+1.
// LDS chunk swizzle: 16B-chunk ^= (row&7), applied on global source AND read.
// Epilogue: acc -> per-wave 16KB LDS tile -> 128B-contiguous bf16 row stores.
template<int ACT, int BIAS>
__global__ __launch_bounds__(512, 2)
void k_gemm256(const bf16* __restrict__ A, const bf16* __restrict__ B,
               const float* __restrict__ bias, bf16* __restrict__ C,
               int M, int N, int NB, int K, int lda, int ldb, int ldc,
               long long sA, long long sB, long long sC)
{
  __shared__ __align__(16) char smem[131072];   // A:[2][32KB] @0, B:[2][32KB] @64KB
  const int bz = blockIdx.z;
  const bf16* Ab = A + (long long)bz * sA;
  const bf16* Bb = B + (long long)bz * sB;
  bf16* Cb = C + (long long)bz * sC;

  // block swizzle: XCD-bijective then GM supertile over M
  const int gx = gridDim.x, gy = gridDim.y;
  const int nwg = gx * gy;
  int orig = blockIdx.y * gx + blockIdx.x;
  {
    const int q8 = nwg >> 3, r8 = nwg & 7;
    const int xcd = orig & 7, idx = orig >> 3;
    orig = (xcd < r8 ? xcd * (q8 + 1) : r8 * (q8 + 1) + (xcd - r8) * q8) + idx;
  }
  const int GM = 8;
  const int per_g = GM * gx;
  const int g = orig / per_g, rem = orig - g * per_g;
  int gsz = gy - g * GM; if (gsz > GM) gsz = GM;
  const int mi = g * GM + rem % gsz;
  const int ni = rem / gsz;
  const int m0 = mi * 256, n0 = ni * 256;

  const int tid = threadIdx.x, lane = tid & 63, wave = tid >> 6;
  const int wm = (wave >> 2) * 128, wn = (wave & 3) * 64;
  const int fr = lane & 15, fg = lane >> 4;
  const int cS0 = ((fg) ^ (fr & 7)) * 16;        // swizzled byte off, ksub 0
  const int cS1 = ((4 + fg) ^ (fr & 7)) * 16;    // ksub 1

  // stage source pointers (per lane): granule = half-operand (128 rows x 64)
  const bf16* pA[2][2]; const bf16* pB[2][2];
  #pragma unroll
  for (int L = 0; L < 2; L++) {
    const int ch = L * 512 + tid;
    const int lr = ch >> 3;
    #pragma unroll
    for (int mh = 0; mh < 2; mh++) {
      int r = (lr & 63) + mh * 64 + ((lr & 64) << 1);
      int cs = (ch & 7) ^ (r & 7);
      int gr = m0 + r; if (gr > M - 1) gr = M - 1;
      pA[mh][L] = Ab + (long long)gr * lda + cs * 8;
    }
    #pragma unroll
    for (int nh = 0; nh < 2; nh++) {
      int r = nh * 32 + (lr & 31) + ((lr >> 5) << 6);
      int cs = (ch & 7) ^ (r & 7);
      int gr = n0 + r; if (gr > NB - 1) gr = NB - 1;
      pB[nh][L] = Bb + (long long)gr * ldb + cs * 8;
    }
  }

  #define STG_A(mh, buf, kk) do {                                        \
    char* d_ = smem + (buf) * 32768 + ((mh) * 64 + wave * 8) * 128;      \
    gload16(pA[mh][0] + (kk), d_);                                       \
    gload16(pA[mh][1] + (kk), d_ + 16384);                               \
  } while (0)
  #define STG_B(nh, buf, kk) do {                                        \
    char* d_ = smem + 65536 + (buf) * 32768 +                            \
               ((nh) * 32 + (wave & 3) * 8 + (wave >> 2) * 64) * 128;    \
    gload16(pB[nh][0] + (kk), d_);                                       \
    gload16(pB[nh][1] + (kk), d_ + 16384);                               \
  } while (0)

  f32x4 acc[8][4];
  #pragma unroll
  for (int i = 0; i < 8; i++)
    #pragma unroll
    for (int j = 0; j < 4; j++) acc[i][j] = (f32x4){0.f, 0.f, 0.f, 0.f};

  const int nt = K / 64;
  // prologue: tile 0 -> buf 0, granule order A0,B0,A1,B1
  STG_A(0, 0, 0); STG_B(0, 0, 0); STG_A(1, 0, 0); STG_B(1, 0, 0);

  #define PHASE_BODY(mh, nh, STAGE_STMT) do {                                 \
    short8 a_[4][2], b_[2][2];                                                \
    _Pragma("unroll")                                                         \
    for (int i = 0; i < 4; i++) {                                             \
      const char* p_ = Ab_l + (wm + (mh) * 64 + i * 16 + fr) * 128;           \
      a_[i][0] = *(const short8*)(p_ + cS0);                                  \
      a_[i][1] = *(const short8*)(p_ + cS1);                                  \
    }                                                                         \
    _Pragma("unroll")                                                         \
    for (int j = 0; j < 2; j++) {                                             \
      const char* p_ = Bb_l + (wn + (nh) * 32 + j * 16 + fr) * 128;           \
      b_[j][0] = *(const short8*)(p_ + cS0);                                  \
      b_[j][1] = *(const short8*)(p_ + cS1);                                  \
    }                                                                         \
    STAGE_STMT;                                                               \
    __builtin_amdgcn_s_setprio(1);                                            \
    _Pragma("unroll")                                                         \
    for (int i = 0; i < 4; i++)                                               \
      _Pragma("unroll")                                                       \
      for (int j = 0; j < 2; j++) {                                           \
        acc[(mh)*4+i][(nh)*2+j] = __builtin_amdgcn_mfma_f32_16x16x32_bf16(    \
            a_[i][0], b_[j][0], acc[(mh)*4+i][(nh)*2+j], 0, 0, 0);            \
        acc[(mh)*4+i][(nh)*2+j] = __builtin_amdgcn_mfma_f32_16x16x32_bf16(    \
            a_[i][1], b_[j][1], acc[(mh)*4+i][(nh)*2+j], 0, 0, 0);            \
      }                                                                       \
    __builtin_amdgcn_s_setprio(0);                                            \
  } while (0)

  for (int t = 0; t < nt; ++t) {
    const int buf = t & 1, nb = buf ^ 1;
    const int kn = (t + 1) * 64;
    const bool pf = (t + 1 < nt);
    const char* Ab_l = smem + buf * 32768;
    const char* Bb_l = smem + 65536 + buf * 32768;

    // phase 0: (mh0,nh0) needs A0,B0
    asm volatile("s_waitcnt vmcnt(4)" ::: "memory");
    __builtin_amdgcn_s_barrier();
    PHASE_BODY(0, 0, { if (pf) STG_A(0, nb, kn); });

    // phase 1: (mh1,nh0) needs A1
    if (pf) { asm volatile("s_waitcnt vmcnt(4)" ::: "memory"); }
    else    { asm volatile("s_waitcnt vmcnt(2)" ::: "memory"); }
    __builtin_amdgcn_s_barrier();
    PHASE_BODY(1, 0, { if (pf) STG_B(0, nb, kn); });

    // phase 2: (mh1,nh1) needs B1
    if (pf) { asm volatile("s_waitcnt vmcnt(4)" ::: "memory"); }
    else    { asm volatile("s_waitcnt vmcnt(0)" ::: "memory"); }
    __builtin_amdgcn_s_barrier();
    PHASE_BODY(1, 1, { if (pf) STG_A(1, nb, kn); });

    // phase 3: (mh0,nh1) all present
    __builtin_amdgcn_s_barrier();
    PHASE_BODY(0, 1, { if (pf) STG_B(1, nb, kn); });
  }
  #undef PHASE_BODY
  #undef STG_A
  #undef STG_B

  // ---- epilogue: acc -> per-wave LDS tile -> coalesced bf16 stores ----
  asm volatile("s_waitcnt vmcnt(0)" ::: "memory");
  __builtin_amdgcn_s_barrier();
  float bv[4];
  #pragma unroll
  for (int j = 0; j < 4; j++) {
    int c = n0 + wn + j * 16 + fr;
    bv[j] = (BIAS && c < N) ? bias[c] : 0.f;
  }
  bf16* epi = (bf16*)(smem + wave * 16384);
  #pragma unroll
  for (int i = 0; i < 8; i++)
    #pragma unroll
    for (int j = 0; j < 4; j++)
      #pragma unroll
      for (int r = 0; r < 4; r++) {
        float v = acc[i][j][r];
        if (BIAS) v += bv[j];
        if (ACT == 1) v = geluf(v);
        else if (ACT == 2) v = eluf(v);
        epi[(i * 16 + fg * 4 + r) * 64 + j * 16 + fr] = f2bf(v);
      }
  #pragma unroll
  for (int it = 0; it < 16; it++) {
    int lrow = it * 8 + (lane >> 3);
    int grow = m0 + wm + lrow;
    int gcol = n0 + wn + (lane & 7) * 8;
    if (grow < M && gcol < N)
      *(short8*)(Cb + (long long)grow * ldc + gcol) =
          *(const short8*)(epi + lrow * 64 + (lane & 7) * 8);
  }
}

// ---------------- 128-tile NT GEMM (kept for small-M split-K) ----------------
template<int ACT, int BIAS, int OBF, int TROUT>
__global__ __launch_bounds__(256)
void k_gemm_nt(const bf16* __restrict__ A, const bf16* __restrict__ B,
               const float* __restrict__ bias, void* __restrict__ Cv,
               int M, int N, int K, int lda, int ldb, int ldc,
               long long sA, long long sB, long long sC, int nsplit, int ks)
{
  __shared__ __align__(16) bf16 As[3][128*32];
  __shared__ __align__(16) bf16 Bs[3][128*32];
  const int zb = blockIdx.z;
  const int b  = zb / nsplit;
  const int sl = zb - b*nsplit;
  const int kbeg = sl * ks;
  int kend = kbeg + ks; if (kend > K) kend = K;
  const int nt = (kend > kbeg) ? (kend - kbeg + 31) / 32 : 0;

  const bf16* Ab = A + (long long)b * sA;
  const bf16* Bb = B + (long long)b * sB;
  const long long cbase = (long long)b * sC;

  const int NTt = gridDim.x, MTt = gridDim.y;
  const int nwg = NTt * MTt;
  int orig = blockIdx.y * NTt + blockIdx.x;
  {
    const int q8 = nwg >> 3, r8 = nwg & 7;
    const int xcd = orig & 7, idx = orig >> 3;
    orig = (xcd < r8 ? xcd * (q8 + 1) : r8 * (q8 + 1) + (xcd - r8) * q8) + idx;
  }
  const int GM = 8;
  const int per_g = GM * NTt;
  const int g = orig / per_g, rem = orig - g * per_g;
  int gsz = MTt - g * GM; if (gsz > GM) gsz = GM;
  const int mi = g * GM + rem % gsz;
  const int ni = rem / gsz;

  const int m0 = mi * 128, n0 = ni * 128;
  const int tid = threadIdx.x, lane = tid & 63, wave = tid >> 6;
  const int wm = (wave >> 1) * 64, wn = (wave & 1) * 64;
  const int fr = lane & 15, fg = lane >> 4;
  const int fgs = fg ^ ((fr >> 1) & 3);

  f32x4 acc[4][4];
  #pragma unroll
  for (int i = 0; i < 4; i++)
    #pragma unroll
    for (int j = 0; j < 4; j++) acc[i][j] = (f32x4){0.f, 0.f, 0.f, 0.f};

  const int c0 = wave * 128 + lane;
  const int c1 = c0 + 64;
  const int rA0 = c0 >> 2, rA1 = c1 >> 2;
  const int cc0 = ((c0 & 3) ^ ((rA0 >> 1) & 3)) * 8;
  const int cc1 = ((c1 & 3) ^ ((rA1 >> 1) & 3)) * 8;
  int gra0 = m0 + rA0; if (gra0 >= M) gra0 = M - 1;
  int gra1 = m0 + rA1; if (gra1 >= M) gra1 = M - 1;
  int grb0 = n0 + rA0; if (grb0 >= N) grb0 = N - 1;
  int grb1 = n0 + rA1; if (grb1 >= N) grb1 = N - 1;
  const bf16* pa0 = Ab + (long long)gra0 * lda + cc0;
  const bf16* pa1 = Ab + (long long)gra1 * lda + cc1;
  const bf16* pb0 = Bb + (long long)grb0 * ldb + cc0;
  const bf16* pb1 = Bb + (long long)grb1 * ldb + cc1;

  char* lA = (char*)&As[0][0] + wave * 2048;
  char* lB = (char*)&Bs[0][0] + wave * 2048;

  #define STAGE(buf, kk) do {                       \
    char* a_ = lA + (buf) * 8192;                   \
    char* b_ = lB + (buf) * 8192;                   \
    gload16(pa0 + (kk), a_);                        \
    gload16(pa1 + (kk), a_ + 1024);                 \
    gload16(pb0 + (kk), b_);                        \
    gload16(pb1 + (kk), b_ + 1024);                 \
  } while (0)

  if (nt > 0) STAGE(0, kbeg);
  if (nt > 1) STAGE(1, kbeg + 32);

  int cur = 0;
  for (int t = 0; t < nt; t++) {
    if (t + 2 < nt) {
      int n2 = cur + 2; if (n2 >= 3) n2 -= 3;
      STAGE(n2, kbeg + (t + 2) * 32);
      asm volatile("s_waitcnt vmcnt(8)" ::: "memory");
    } else if (t + 1 < nt) {
      asm volatile("s_waitcnt vmcnt(4)" ::: "memory");
    } else {
      asm volatile("s_waitcnt vmcnt(0)" ::: "memory");
    }
    __builtin_amdgcn_s_barrier();

    const bf16* Asb = (const bf16*)((const char*)&As[0][0] + cur * 8192);
    const bf16* Bsb = (const bf16*)((const char*)&Bs[0][0] + cur * 8192);
    short8 af[4], bfv[4];
    #pragma unroll
    for (int i = 0; i < 4; i++) {
      af[i]  = *(const short8*)(Asb + (wm + i * 16 + fr) * 32 + fgs * 8);
      bfv[i] = *(const short8*)(Bsb + (wn + i * 16 + fr) * 32 + fgs * 8);
    }
    #pragma unroll
    for (int i = 0; i < 4; i++)
      #pragma unroll
      for (int j = 0; j < 4; j++)
        acc[i][j] = __builtin_amdgcn_mfma_f32_16x16x32_bf16(af[i], bfv[j], acc[i][j], 0, 0, 0);

    asm volatile("s_waitcnt lgkmcnt(0)" ::: "memory");
    __builtin_amdgcn_s_barrier();
    cur = cur + 1; if (cur >= 3) cur = 0;
  }
  #undef STAGE

  #pragma unroll
  for (int i = 0; i < 4; i++) {
    const int r0 = m0 + wm + i * 16 + fg * 4;
    #pragma unroll
    for (int j = 0; j < 4; j++) {
      const int col = n0 + wn + j * 16 + fr;
      if (col >= N) continue;
      float bv = 0.f;
      if (BIAS) bv = bias[col];
      #pragma unroll
      for (int r = 0; r < 4; r++) {
        const int row = r0 + r;
        if (row >= M) continue;
        float v = acc[i][j][r] + bv;
        if (ACT == 1) v = geluf(v);
        else if (ACT == 2) v = eluf(v);
        long long off;
        if (TROUT) off = cbase + (long long)col * ldc + row;
        else       off = cbase + (long long)row * ldc + col;
        if (OBF == 1)      ((bf16*)Cv)[off] = f2bf(v);
        else if (OBF == 2) atomicAdd(&((float*)Cv)[off], v);
        else               ((float*)Cv)[off] = v;
      }
    }
  }
}

// ---------------- small utility kernels ----------------
__global__ void k_zero(float* p, long long n) {
  long long i = (long long)blockIdx.x * blockDim.x + threadIdx.x;
  long long st = (long long)gridDim.x * blockDim.x;
  for (; i < n; i += st) p[i] = 0.f;
}

__global__ void k_f2bf(const float* __restrict__ in, bf16* __restrict__ out, long long n) {
  long long i = (long long)blockIdx.x * 256 + threadIdx.x;
  if (i < n) out[i] = f2bf(in[i]);
}

// h0 = bf16(x + ns_emb), float4-vectorized
__global__ void k_add_emb(const float* __restrict__ x, const float* __restrict__ ns,
                          bf16* __restrict__ h0, long long n4) {
  long long i = (long long)blockIdx.x * 256 + threadIdx.x;
  long long st = (long long)gridDim.x * 256;
  for (; i < n4; i += st) {
    float4 v = ((const float4*)x)[i];
    int d = (int)(i % (DE / 4)) * 4;
    short4_t o;
    o.x = bfbits(v.x + ns[d]);
    o.y = bfbits(v.y + ns[d + 1]);
    o.z = bfbits(v.z + ns[d + 2]);
    o.w = bfbits(v.w + ns[d + 3]);
    ((short4_t*)h0)[i] = o;
  }
}

// transpose f32 [R,C] -> bf16 [C,R]; R,C multiples of 32
__global__ void k_transpose_bf(const float* __restrict__ W, bf16* __restrict__ Wt, int R, int C) {
  __shared__ float t[32][33];
  int c0 = blockIdx.x * 32, r0 = blockIdx.y * 32;
  int x = threadIdx.x, y = threadIdx.y;
  #pragma unroll
  for (int j = 0; j < 32; j += 8)
    t[y + j][x] = W[(long long)(r0 + y + j) * C + c0 + x];
  __syncthreads();
  #pragma unroll
  for (int j = 0; j < 32; j += 8)
    Wt[(long long)(c0 + y + j) * R + r0 + x] = f2bf(t[x][y + j]);
}

// transpose bf16 v[Nv][DE] -> vT[DE][NPAD], zero-fill rows >= Nv
__global__ void k_transpose_v(const bf16* __restrict__ v, bf16* __restrict__ vT, int Nv) {
  __shared__ bf16 t[32][34];
  int n0 = blockIdx.x * 32, d0 = blockIdx.y * 32;
  int x = threadIdx.x, y = threadIdx.y;
  #pragma unroll
  for (int j = 0; j < 32; j += 8) {
    int n = n0 + y + j;
    t[y + j][x] = (n < Nv) ? v[(long long)n * DE + d0 + x] : f2bf(0.f);
  }
  __syncthreads();
  #pragma unroll
  for (int j = 0; j < 32; j += 8)
    vT[(long long)(d0 + y + j) * NPAD + n0 + x] = t[x][y + j];
}

// es/ed per node: block = 512 threads, wave w = head
__global__ __launch_bounds__(512)
void k_esed(const bf16* __restrict__ hh, const float* __restrict__ asrc,
            const float* __restrict__ adst, float* __restrict__ es, float* __restrict__ ed) {
  int n = blockIdx.x;
  int h = threadIdx.x >> 6;
  int c = threadIdx.x & 63;
  float v = bf2f(hh[(long long)n * HD + h * 64 + c]);
  float s = v * asrc[h * 64 + c];
  float d = v * adst[h * 64 + c];
  #pragma unroll
  for (int o = 32; o; o >>= 1) { s += __shfl_down(s, o, 64); d += __shfl_down(d, o, 64); }
  if (c == 0) { es[n * 8 + h] = s; ed[n * 8 + h] = d; }
}

__global__ void k_edge_logits(const int* __restrict__ ei, int E, int TOT,
                              const float* __restrict__ es, const float* __restrict__ ed,
                              float* __restrict__ logits, unsigned* __restrict__ mkey) {
  int e = blockIdx.x * 256 + threadIdx.x;
  if (e >= TOT) return;
  int s, d;
  if (e < E) { s = ei[e]; d = ei[E + e]; } else { s = d = e - E; }
  #pragma unroll
  for (int h = 0; h < 8; h++) {
    float l = es[s * 8 + h] + ed[d * 8 + h];
    l = l > 0.f ? l : 0.2f * l;
    logits[(long long)e * 8 + h] = l;
    unsigned u = __float_as_uint(l);
    unsigned key = (u & 0x80000000u) ? ~u : (u | 0x80000000u);
    atomicMax(&mkey[d * 8 + h], key);
  }
}

__global__ void k_edge_exp(const int* __restrict__ ei, int E, int TOT,
                           const unsigned* __restrict__ mkey, float* __restrict__ logits,
                           float* __restrict__ den) {
  int e = blockIdx.x * 256 + threadIdx.x;
  if (e >= TOT) return;
  int d = (e < E) ? ei[E + e] : (e - E);
  #pragma unroll
  for (int h = 0; h < 8; h++) {
    unsigned key = mkey[d * 8 + h];
    unsigned u = (key & 0x80000000u) ? (key & 0x7fffffffu) : ~key;
    float m = __uint_as_float(u);
    float ex = expf(logits[(long long)e * 8 + h] - m);
    logits[(long long)e * 8 + h] = ex;
    atomicAdd(&den[d * 8 + h], ex);
  }
}

__global__ __launch_bounds__(256)
void k_edge_aggr(const int* __restrict__ ei, int E, int TOT,
                 const float* __restrict__ logits, const float* __restrict__ den,
                 const bf16* __restrict__ hh, float* __restrict__ accum) {
  int base = blockIdx.x * 4;
  for (int u = 0; u < 4; u++) {
    int e = base + u;
    if (e >= TOT) break;
    int s, d;
    if (e < E) { s = ei[e]; d = ei[E + e]; } else { s = d = e - E; }
    #pragma unroll
    for (int half = 0; half < 2; half++) {
      int idx = threadIdx.x + half * 256;
      int h = idx >> 6;
      float alpha = logits[(long long)e * 8 + h] / (den[d * 8 + h] + 1e-16f);
      float v = bf2f(hh[(long long)s * HD + idx]) * alpha;
      atomicAdd(&accum[(long long)d * HD + idx], v);
    }
  }
}

template<int ACT>
__global__ void k_gat_fin(const float* __restrict__ accum, const float* __restrict__ b,
                          bf16* __restrict__ out) {
  int i = blockIdx.x * 256 + threadIdx.x;
  long long n = blockIdx.y;
  float v = accum[n * HD + i] + b[i];
  if (ACT == 2) v = eluf(v);
  out[n * HD + i] = f2bf(v);
}

template<int ACT, int BIAS, int TOBF>
__global__ void k_postproc(float* __restrict__ acc, const float* __restrict__ bias,
                           bf16* __restrict__ obf, long long tot, int cols) {
  long long i = (long long)blockIdx.x * 256 + threadIdx.x;
  if (i >= tot) return;
  int c = (int)(i % cols);
  float v = acc[i];
  if (BIAS) v += bias[c];
  if (ACT == 1) v = geluf(v);
  if (TOBF) obf[i] = f2bf(v);
  else acc[i] = v;
}

// row softmax (in-place capable): scores bf16 [rows][NPAD], scale folded
__global__ __launch_bounds__(256)
void k_softmax_row(const bf16* s_all, bf16* a_all, int NV) {
  long long row = blockIdx.x;
  const bf16* s = s_all + row * NPAD;
  bf16* a = a_all + row * NPAD;
  int tid = threadIdx.x;
  __shared__ float red[4];
  float mx = -3.0e38f;
  for (int c = tid; c < NV; c += 256) mx = fmaxf(mx, bf2f(s[c]));
  #pragma unroll
  for (int o = 32; o; o >>= 1) mx = fmaxf(mx, __shfl_down(mx, o, 64));
  if ((tid & 63) == 0) red[tid >> 6] = mx;
  __syncthreads();
  mx = fmaxf(fmaxf(red[0], red[1]), fmaxf(red[2], red[3]));
  const float inv = 0.05590169943749474f;  // 1/sqrt(320)
  float sm = 0.f;
  for (int c = tid; c < NV; c += 256) sm += expf((bf2f(s[c]) - mx) * inv);
  #pragma unroll
  for (int o = 32; o; o >>= 1) sm += __shfl_down(sm, o, 64);
  __syncthreads();
  if ((tid & 63) == 0) red[tid >> 6] = sm;
  __syncthreads();
  sm = red[0] + red[1] + red[2] + red[3];
  float rs = 1.f / sm;
  for (int c = tid; c < NPAD; c += 256) {
    float v = (c < NV) ? expf((bf2f(s[c]) - mx) * inv) * rs : 0.f;
    a[c] = f2bf(v);
  }
}

// LayerNorm(a+b) row of DE, optional bf16 dup
template<int WB>
__global__ __launch_bounds__(256)
void k_ln(const float* __restrict__ a, const float* __restrict__ b,
          const float* __restrict__ g, const float* __restrict__ bt,
          float* __restrict__ out, bf16* __restrict__ obf) {
  long long row = blockIdx.x;
  __shared__ float xs[DE];
  __shared__ float red[4];
  int tid = threadIdx.x;
  float sum = 0.f;
  for (int c = tid; c < DE; c += 256) {
    float v = a[row * DE + c] + b[row * DE + c];
    xs[c] = v; sum += v;
  }
  #pragma unroll
  for (int o = 32; o; o >>= 1) sum += __shfl_down(sum, o, 64);
  if ((tid & 63) == 0) red[tid >> 6] = sum;
  __syncthreads();
  float mean = (red[0] + red[1] + red[2] + red[3]) * (1.f / DE);
  float vs = 0.f;
  for (int c = tid; c < DE; c += 256) { float t = xs[c] - mean; vs += t * t; }
  #pragma unroll
  for (int o = 32; o; o >>= 1) vs += __shfl_down(vs, o, 64);
  __syncthreads();
  if ((tid & 63) == 0) red[tid >> 6] = vs;
  __syncthreads();
  float var = (red[0] + red[1] + red[2] + red[3]) * (1.f / DE);
  float sc = rsqrtf(var + 1e-5f);
  for (int c = tid; c < DE; c += 256) {
    float v = (xs[c] - mean) * sc * g[c] + bt[c];
    out[row * DE + c] = v;
    if (WB) obf[row * DE + c] = f2bf(v);
  }
}

// ---------------- host ----------------
extern "C" void kernel_launch(void* const* d_in, const int* in_sizes, int n_in,
                              void* d_out, int out_size, void* d_ws, size_t ws_size,
                              hipStream_t stream)
{
  const float* x       = (const float*)d_in[0];
  const int*   ei      = (const int*)d_in[1];
  const float* ns_emb  = (const float*)d_in[2];
  const float* gat_w0  = (const float*)d_in[3];
  const float* gat_wr  = (const float*)d_in[4];
  const float* a_src   = (const float*)d_in[5];
  const float* a_dst   = (const float*)d_in[6];
  const float* gat_b   = (const float*)d_in[7];
  const float* proj_w1 = (const float*)d_in[8];
  const float* proj_b1 = (const float*)d_in[9];
  const float* proj_w2 = (const float*)d_in[10];
  const float* proj_b2 = (const float*)d_in[11];
  const float* queries = (const float*)d_in[12];
  const float* wq = (const float*)d_in[13]; const float* bq = (const float*)d_in[14];
  const float* wk = (const float*)d_in[15]; const float* bk = (const float*)d_in[16];
  const float* wv = (const float*)d_in[17]; const float* bv = (const float*)d_in[18];
  const float* wo = (const float*)d_in[19]; const float* bo = (const float*)d_in[20];
  const float* ln1g = (const float*)d_in[21]; const float* ln1b = (const float*)d_in[22];
  const float* fw1 = (const float*)d_in[23]; const float* fb1 = (const float*)d_in[24];
  const float* fw2 = (const float*)d_in[25]; const float* fb2 = (const float*)d_in[26];
  const float* ln2g = (const float*)d_in[27]; const float* ln2b = (const float*)d_in[28];
  float* out = (float*)d_out;

  const int N = in_sizes[0] / DE;   // 30000
  const int E = in_sizes[1] / 2;    // 90000
  const int TOT = E + N;            // 120000
  const int MT  = (N + 127) / 128;  // 128-tile M count (old kernel)
  const int MT2 = (N + 255) / 256;  // 256-tile M count (118)

  char* base = (char*)d_ws;
  size_t off = 0;
  auto AL = [&](size_t bytes) -> void* {
    void* p = base + off;
    off += (bytes + 255) & ~(size_t)255;
    return p;
  };
  bf16* wt_g0 = (bf16*)AL((size_t)HD * DE * 2);
  bf16* wt_g1 = (bf16*)AL((size_t)HD * HD * 2);
  bf16* wt_g2 = (bf16*)AL((size_t)HD * HD * 2);
  bf16* wt_p1 = (bf16*)AL((size_t)HD * HD * 2);
  bf16* wt_p2 = (bf16*)AL((size_t)DE * HD * 2);
  bf16* wt_q  = (bf16*)AL((size_t)DE * DE * 2);
  bf16* wt_k  = (bf16*)AL((size_t)DE * DE * 2);
  bf16* wt_v  = (bf16*)AL((size_t)DE * DE * 2);
  bf16* wt_o  = (bf16*)AL((size_t)DE * DE * 2);
  bf16* wt_f1 = (bf16*)AL((size_t)4 * DE * DE * 2);
  bf16* wt_f2 = (bf16*)AL((size_t)4 * DE * DE * 2);
  bf16* big0  = (bf16*)AL((size_t)N * DE * 2);      // h0 -> hD
  bf16* big1  = (bf16*)AL((size_t)N * DE * 2);      // k  -> v(normal)
  bf16* vT    = (bf16*)AL((size_t)DE * NPAD * 2);
  // GAT scratch block (contiguous; overlaid by `sc` in attention phase)
  bf16* hhA   = (bf16*)AL((size_t)N * HD * 2);
  bf16* hB    = (bf16*)AL((size_t)N * HD * 2);
  float* accum  = (float*)AL((size_t)N * HD * 4);
  float* logits = (float*)AL((size_t)TOT * 8 * 4);
  unsigned* mkey = (unsigned*)AL((size_t)N * 8 * 4);
  float* den = (float*)AL((size_t)N * 8 * 4);
  float* es  = (float*)AL((size_t)N * 8 * 4);
  float* edv = (float*)AL((size_t)N * 8 * 4);
  bf16* sc = (bf16*)hhA;  // scores/attn [8][QNUM][NPAD] bf16 = 96MB < 130MB block
  // small f32 pool (zeroed once; targets of split-K atomic GEMMs)
  float* q_f     = (float*)AL((size_t)QNUM * DE * 4);
  float* ctx_f   = (float*)AL((size_t)QNUM * DE * 4);
  float* attnout = (float*)AL((size_t)QNUM * DE * 4);
  float* f1_f    = (float*)AL((size_t)QNUM * 4 * DE * 4);
  float* f2_f    = (float*)AL((size_t)QNUM * DE * 4);
  bf16* qs_bf  = (bf16*)AL((size_t)QNUM * DE * 2);
  bf16* q_bf   = (bf16*)AL((size_t)QNUM * DE * 2);
  bf16* ctx_bf = (bf16*)AL((size_t)QNUM * DE * 2);
  float* attended = (float*)AL((size_t)QNUM * DE * 4);
  bf16* att_bf = (bf16*)AL((size_t)QNUM * DE * 2);
  bf16* f1_bf  = (bf16*)AL((size_t)QNUM * 4 * DE * 2);

  dim3 blk(256);
  dim3 tblk(32, 8);

  // weight convert+transpose to bf16 [out,in]
  k_transpose_bf<<<dim3(HD / 32, DE / 32), tblk, 0, stream>>>(gat_w0, wt_g0, DE, HD);
  k_transpose_bf<<<dim3(HD / 32, HD / 32), tblk, 0, stream>>>(gat_wr, wt_g1, HD, HD);
  k_transpose_bf<<<dim3(HD / 32, HD / 32), tblk, 0, stream>>>(gat_wr + (size_t)HD * HD, wt_g2, HD, HD);
  k_transpose_bf<<<dim3(HD / 32, HD / 32), tblk, 0, stream>>>(proj_w1, wt_p1, HD, HD);
  k_transpose_bf<<<dim3(DE / 32, HD / 32), tblk, 0, stream>>>(proj_w2, wt_p2, HD, DE);
  k_transpose_bf<<<dim3(DE / 32, DE / 32), tblk, 0, stream>>>(wq, wt_q, DE, DE);
  k_transpose_bf<<<dim3(DE / 32, DE / 32), tblk, 0, stream>>>(wk, wt_k, DE, DE);
  k_transpose_bf<<<dim3(DE / 32, DE / 32), tblk, 0, stream>>>(wv, wt_v, DE, DE);
  k_transpose_bf<<<dim3(DE / 32, DE / 32), tblk, 0, stream>>>(wo, wt_o, DE, DE);
  k_transpose_bf<<<dim3(4 * DE / 32, DE / 32), tblk, 0, stream>>>(fw1, wt_f1, DE, 4 * DE);
  k_transpose_bf<<<dim3(DE / 32, 4 * DE / 32), tblk, 0, stream>>>(fw2, wt_f2, 4 * DE, DE);

  k_add_emb<<<dim3(2048), blk, 0, stream>>>(x, ns_emb, big0, (long long)N * DE / 4);
  k_f2bf<<<dim3((QNUM * DE + 255) / 256), blk, 0, stream>>>(queries, qs_bf, (long long)QNUM * DE);
  {
    long long pool = (long long)QNUM * DE * 4 + (long long)QNUM * 4 * DE;
    k_zero<<<dim3(1024), blk, 0, stream>>>(q_f, pool);
  }

  // ---- GAT layers (256-tile 8-phase GEMM) ----
  const bf16* gw[3] = { wt_g0, wt_g1, wt_g2 };
  const long long zcnt = (long long)N * HD + (long long)TOT * 8 + (long long)N * 16;
  for (int l = 0; l < 3; l++) {
    const bf16* Ain = (l == 0) ? big0 : hB;
    int Kd = (l == 0) ? DE : HD;
    k_gemm256<0,0><<<dim3(2, MT2), dim3(512), 0, stream>>>(Ain, gw[l], nullptr, hhA,
        N, HD, HD, Kd, Kd, Kd, HD, 0, 0, 0);
    k_zero<<<dim3(2048), blk, 0, stream>>>(accum, zcnt);
    k_esed<<<dim3(N), dim3(512), 0, stream>>>(hhA, a_src + l * HD, a_dst + l * HD, es, edv);
    k_edge_logits<<<dim3((TOT + 255) / 256), blk, 0, stream>>>(ei, E, TOT, es, edv, logits, mkey);
    k_edge_exp<<<dim3((TOT + 255) / 256), blk, 0, stream>>>(ei, E, TOT, mkey, logits, den);
    k_edge_aggr<<<dim3((TOT + 3) / 4), blk, 0, stream>>>(ei, E, TOT, logits, den, hhA, accum);
    if (l < 2) k_gat_fin<2><<<dim3(2, N), blk, 0, stream>>>(accum, gat_b + l * HD, hB);
    else       k_gat_fin<0><<<dim3(2, N), blk, 0, stream>>>(accum, gat_b + l * HD, hB);
  }

  // ---- projection ----
  k_gemm256<1,1><<<dim3(2, MT2), dim3(512), 0, stream>>>(hB, wt_p1, proj_b1, hhA,
      N, HD, HD, HD, HD, HD, HD, 0, 0, 0);
  k_gemm256<0,1><<<dim3(10, MT2), dim3(512), 0, stream>>>(hhA, wt_p2, proj_b2, big0,
      N, DE, DE, HD, HD, HD, DE, 0, 0, 0);

  // ---- q (old split-K), k ----
  k_gemm_nt<0,0,2,0><<<dim3(20, 2, 8), blk, 0, stream>>>(qs_bf, wt_q, nullptr, q_f,
      QNUM, DE, DE, DE, DE, DE, 0, 0, 0, 8, 320);
  k_postproc<0,1,1><<<dim3((QNUM * DE + 255) / 256), blk, 0, stream>>>(q_f, bq, q_bf,
      (long long)QNUM * DE, DE);
  k_gemm256<0,1><<<dim3(10, MT2), dim3(512), 0, stream>>>(big0, wt_k, bk, big1,
      N, DE, DE, DE, DE, DE, DE, 0, 0, 0);

  // ---- scores (overlay buffer), then v -> big1, transpose, softmax, ctx ----
  k_gemm256<0,0><<<dim3((NPAD + 255) / 256, 1, 8), dim3(512), 0, stream>>>(q_bf, big1, nullptr, sc,
      QNUM, NPAD, N, ADHD, DE, DE, NPAD, 320, 320, (long long)QNUM * NPAD);
  k_gemm256<0,1><<<dim3(10, MT2), dim3(512), 0, stream>>>(big0, wt_v, bv, big1,
      N, DE, DE, DE, DE, DE, DE, 0, 0, 0);
  k_transpose_v<<<dim3(NPAD / 32, DE / 32), tblk, 0, stream>>>(big1, vT, N);
  k_softmax_row<<<dim3(8 * QNUM), blk, 0, stream>>>(sc, sc, N);
  k_gemm_nt<0,0,2,0><<<dim3(3, 2, 8 * 32), blk, 0, stream>>>(sc, vT, nullptr, ctx_f,
      QNUM, ADHD, NPAD, NPAD, NPAD, DE, (long long)QNUM * NPAD, (long long)ADHD * NPAD, 320, 32, 960);
  k_postproc<0,0,1><<<dim3((QNUM * DE + 255) / 256), blk, 0, stream>>>(ctx_f, nullptr, ctx_bf,
      (long long)QNUM * DE, DE);

  // ---- output projection + LN1 ----
  k_gemm_nt<0,0,2,0><<<dim3(20, 2, 8), blk, 0, stream>>>(ctx_bf, wt_o, nullptr, attnout,
      QNUM, DE, DE, DE, DE, DE, 0, 0, 0, 8, 320);
  k_postproc<0,1,0><<<dim3((QNUM * DE + 255) / 256), blk, 0, stream>>>(attnout, bo, nullptr,
      (long long)QNUM * DE, DE);
  k_ln<1><<<dim3(QNUM), blk, 0, stream>>>(queries, attnout, ln1g, ln1b, attended, att_bf);

  // ---- FFN + LN2 ----
  k_gemm_nt<0,0,2,0><<<dim3(80, 2, 4), blk, 0, stream>>>(att_bf, wt_f1, nullptr, f1_f,
      QNUM, 4 * DE, DE, DE, DE, 4 * DE, 0, 0, 0, 4, 640);
  k_postproc<1,1,1><<<dim3((QNUM * 4 * DE + 255) / 256), blk, 0, stream>>>(f1_f, fb1, f1_bf,
      (long long)QNUM * 4 * DE, 4 * DE);
  k_gemm_nt<0,0,2,0><<<dim3(20, 2, 8), blk, 0, stream>>>(f1_bf, wt_f2, nullptr, f2_f,
      QNUM, DE, 4 * DE, 4 * DE, 4 * DE, DE, 0, 0, 0, 8, 1280);
  k_postproc<0,1,0><<<dim3((QNUM * DE + 255) / 256), blk, 0, stream>>>(f2_f, fb2, nullptr,
      (long long)QNUM * DE, DE);
  k_ln<0><<<dim3(QNUM), blk, 0, stream>>>(attended, f2_f, ln2g, ln2b, out, nullptr);
}

// Round 4
// 2659.498 us; speedup vs baseline: 1.3533x; 1.0787x over previous
//
#include <hip/hip_runtime.h>
#include <hip/hip_bf16.h>
#include <cmath>

typedef __hip_bfloat16 bf16;
typedef __attribute__((ext_vector_type(8))) short short8;
typedef __attribute__((ext_vector_type(4))) short short4_t;
typedef __attribute__((ext_vector_type(4))) float f32x4;
typedef __attribute__((address_space(1))) void as1_void;
typedef __attribute__((address_space(3))) void as3_void;

#define DE   2560
#define HD   512
#define NPAD 30016
#define QNUM 200
#define ADHD 320

static __device__ __forceinline__ float bf2f(bf16 v){ return __bfloat162float(v); }
static __device__ __forceinline__ bf16  f2bf(float v){ return __float2bfloat16(v); }
static __device__ __forceinline__ short bfbits(float f){ bf16 b = f2bf(f); return *reinterpret_cast<short*>(&b); }
static __device__ __forceinline__ float geluf(float x){ return 0.5f*x*(1.0f+erff(x*0.70710678118654752440f)); }
static __device__ __forceinline__ float eluf(float x){ return x>0.f ? x : expm1f(x); }

static __device__ __forceinline__ void gload16(const void* g, void* l){
  __builtin_amdgcn_global_load_lds((as1_void*)g, (as3_void*)l, 16, 0, 0);
}

// =================== 256x256 8-phase bf16 NT GEMM ===================
// C[M,N](bf16) = act(A[M,K] * B[N,K]^T + bias). BK=64, 512 thr (8 waves 2Mx4N),
// 128KB LDS dbuf. Quadrant order (0,0)->(0,1)->(1,1)->(1,0): each phase reloads
// only the CHANGED operand half (28 ds_read_b128/K-tile vs 48). Counted vmcnt
// (never 0 mid-loop), one granule staged per phase for tile t+1 in need-order
// A0,B0,B1,A1. LDS chunk swizzle on both source and read.
// KV mode: cols >= NK are stored TRANSPOSED into C2 (vT layout [col][NPAD]),
// with rows >= M zeroed (pad region), via per-wave LDS re-tile.
template<int ACT, int BIAS, int KV>
__global__ __launch_bounds__(512, 1)
void k_gemm256(const bf16* __restrict__ A, const bf16* __restrict__ B,
               const float* __restrict__ bias, bf16* __restrict__ C,
               bf16* __restrict__ C2, int NK,
               int M, int N, int NB, int K, int lda, int ldb, int ldc,
               long long sA, long long sB, long long sC)
{
  __shared__ __align__(16) char smem[131072];   // A:[2][32KB] @0, B:[2][32KB] @64KB
  const int bz = blockIdx.z;
  const bf16* Ab = A + (long long)bz * sA;
  const bf16* Bb = B + (long long)bz * sB;
  bf16* Cb = C + (long long)bz * sC;

  // block swizzle: XCD-bijective then GM supertile over M
  const int gx = gridDim.x, gy = gridDim.y;
  const int nwg = gx * gy;
  int orig = blockIdx.y * gx + blockIdx.x;
  {
    const int q8 = nwg >> 3, r8 = nwg & 7;
    const int xcd = orig & 7, idx = orig >> 3;
    orig = (xcd < r8 ? xcd * (q8 + 1) : r8 * (q8 + 1) + (xcd - r8) * q8) + idx;
  }
  const int GM = 8;
  const int per_g = GM * gx;
  const int g = orig / per_g, rem = orig - g * per_g;
  int gsz = gy - g * GM; if (gsz > GM) gsz = GM;
  const int mi = g * GM + rem % gsz;
  const int ni = rem / gsz;
  const int m0 = mi * 256, n0 = ni * 256;

  const int tid = threadIdx.x, lane = tid & 63, wave = tid >> 6;
  const int wm = (wave >> 2) * 128, wn = (wave & 3) * 64;
  const int fr = lane & 15, fg = lane >> 4;
  const int cS0 = ((fg) ^ (fr & 7)) * 16;        // swizzled byte off, ksub 0
  const int cS1 = ((4 + fg) ^ (fr & 7)) * 16;    // ksub 1

  // stage source pointers (per lane): granule = half-operand (128 rows x 64)
  const bf16* pA[2][2]; const bf16* pB[2][2];
  #pragma unroll
  for (int L = 0; L < 2; L++) {
    const int ch = L * 512 + tid;
    const int lr = ch >> 3;
    #pragma unroll
    for (int mh = 0; mh < 2; mh++) {
      int r = (lr & 63) + mh * 64 + ((lr & 64) << 1);
      int cs = (ch & 7) ^ (r & 7);
      int gr = m0 + r; if (gr > M - 1) gr = M - 1;
      pA[mh][L] = Ab + (long long)gr * lda + cs * 8;
    }
    #pragma unroll
    for (int nh = 0; nh < 2; nh++) {
      int r = nh * 32 + (lr & 31) + ((lr >> 5) << 6);
      int cs = (ch & 7) ^ (r & 7);
      int gr = n0 + r; if (gr > NB - 1) gr = NB - 1;
      pB[nh][L] = Bb + (long long)gr * ldb + cs * 8;
    }
  }

  #define STG_A(mh, buf, kk) do {                                        \
    char* d_ = smem + (buf) * 32768 + ((mh) * 64 + wave * 8) * 128;      \
    gload16(pA[mh][0] + (kk), d_);                                       \
    gload16(pA[mh][1] + (kk), d_ + 16384);                               \
  } while (0)
  #define STG_B(nh, buf, kk) do {                                        \
    char* d_ = smem + 65536 + (buf) * 32768 +                            \
               ((nh) * 32 + (wave & 3) * 8 + (wave >> 2) * 64) * 128;    \
    gload16(pB[nh][0] + (kk), d_);                                       \
    gload16(pB[nh][1] + (kk), d_ + 16384);                               \
  } while (0)

  f32x4 acc[8][4];
  #pragma unroll
  for (int i = 0; i < 8; i++)
    #pragma unroll
    for (int j = 0; j < 4; j++) acc[i][j] = (f32x4){0.f, 0.f, 0.f, 0.f};

  const int nt = K / 64;
  // prologue: tile 0 -> buf 0, granule NEED-order A0,B0,B1,A1
  STG_A(0, 0, 0); STG_B(0, 0, 0); STG_B(1, 0, 0); STG_A(1, 0, 0);

  #define LOAD_A(mh) do {                                                \
    _Pragma("unroll")                                                    \
    for (int i = 0; i < 4; i++) {                                        \
      const char* p_ = Ab_l + (wm + (mh) * 64 + i * 16 + fr) * 128;      \
      a_[i][0] = *(const short8*)(p_ + cS0);                             \
      a_[i][1] = *(const short8*)(p_ + cS1);                             \
    }                                                                    \
  } while (0)
  #define LOAD_B(nh) do {                                                \
    _Pragma("unroll")                                                    \
    for (int j = 0; j < 2; j++) {                                        \
      const char* p_ = Bb_l + (wn + (nh) * 32 + j * 16 + fr) * 128;      \
      b_[j][0] = *(const short8*)(p_ + cS0);                             \
      b_[j][1] = *(const short8*)(p_ + cS1);                             \
    }                                                                    \
  } while (0)
  #define MFMA_Q(mh, nh) do {                                            \
    __builtin_amdgcn_s_setprio(1);                                       \
    _Pragma("unroll")                                                    \
    for (int i = 0; i < 4; i++)                                          \
      _Pragma("unroll")                                                  \
      for (int j = 0; j < 2; j++) {                                      \
        acc[(mh)*4+i][(nh)*2+j] = __builtin_amdgcn_mfma_f32_16x16x32_bf16( \
            a_[i][0], b_[j][0], acc[(mh)*4+i][(nh)*2+j], 0, 0, 0);       \
        acc[(mh)*4+i][(nh)*2+j] = __builtin_amdgcn_mfma_f32_16x16x32_bf16( \
            a_[i][1], b_[j][1], acc[(mh)*4+i][(nh)*2+j], 0, 0, 0);       \
      }                                                                  \
    __builtin_amdgcn_s_setprio(0);                                       \
  } while (0)

  for (int t = 0; t < nt; ++t) {
    const int buf = t & 1, nb = buf ^ 1;
    const int kn = (t + 1) * 64;
    const bool pf = (t + 1 < nt);
    const char* Ab_l = smem + buf * 32768;
    const char* Bb_l = smem + 65536 + buf * 32768;
    short8 a_[4][2], b_[2][2];

    // ph0: quadrant (0,0) — needs A0,B0
    asm volatile("s_waitcnt vmcnt(4)" ::: "memory");
    __builtin_amdgcn_s_barrier();
    LOAD_A(0); LOAD_B(0);
    if (pf) STG_A(0, nb, kn);
    MFMA_Q(0, 0);

    // ph1: quadrant (0,1) — reuse a_, needs B1
    if (pf) { asm volatile("s_waitcnt vmcnt(4)" ::: "memory"); }
    else    { asm volatile("s_waitcnt vmcnt(2)" ::: "memory"); }
    __builtin_amdgcn_s_barrier();
    LOAD_B(1);
    if (pf) STG_B(0, nb, kn);
    MFMA_Q(0, 1);

    // ph2: quadrant (1,1) — reuse b_, needs A1
    if (pf) { asm volatile("s_waitcnt vmcnt(4)" ::: "memory"); }
    else    { asm volatile("s_waitcnt vmcnt(0)" ::: "memory"); }
    __builtin_amdgcn_s_barrier();
    LOAD_A(1);
    if (pf) STG_B(1, nb, kn);
    MFMA_Q(1, 1);

    // ph3: quadrant (1,0) — reuse a_, re-read B0 (long landed)
    __builtin_amdgcn_s_barrier();
    LOAD_B(0);
    if (pf) STG_A(1, nb, kn);
    MFMA_Q(1, 0);
  }
  #undef LOAD_A
  #undef LOAD_B
  #undef MFMA_Q
  #undef STG_A
  #undef STG_B

  // ---- epilogue ----
  asm volatile("s_waitcnt vmcnt(0)" ::: "memory");
  __builtin_amdgcn_s_barrier();
  float bv_[4];
  #pragma unroll
  for (int j = 0; j < 4; j++) {
    int c = n0 + wn + j * 16 + fr;
    bv_[j] = (BIAS && c < N) ? bias[c] : 0.f;
  }

  if (KV && n0 >= NK) {
    // transposed store into C2[col'][NPAD], col' = global col - NK; pad rows zeroed
    bf16* epi = (bf16*)(smem + wave * 16384);   // [64 cols][128 rows], row-XOR swz
    #pragma unroll
    for (int i = 0; i < 8; i++)
      #pragma unroll
      for (int j = 0; j < 4; j++)
        #pragma unroll
        for (int r = 0; r < 4; r++) {
          int row = i * 16 + fg * 4 + r;
          int col = j * 16 + fr;
          float v = acc[i][j][r];
          if (BIAS) v += bv_[j];
          if (ACT == 1) v = geluf(v);
          else if (ACT == 2) v = eluf(v);
          if (m0 + wm + row >= M) v = 0.f;
          epi[col * 128 + (row ^ ((col & 7) << 3))] = f2bf(v);
        }
    #pragma unroll
    for (int it = 0; it < 16; it++) {
      int col = it * 4 + (lane >> 4);
      int row0 = (lane & 15) * 8;
      int grow = m0 + wm + row0;
      int gcol = n0 - NK + wn + col;
      if (grow < NPAD)
        *(short8*)(C2 + (long long)gcol * NPAD + grow) =
            *(const short8*)(epi + col * 128 + (row0 ^ ((col & 7) << 3)));
    }
  } else {
    bf16* epi = (bf16*)(smem + wave * 16384);   // [128 rows][64 cols]
    #pragma unroll
    for (int i = 0; i < 8; i++)
      #pragma unroll
      for (int j = 0; j < 4; j++)
        #pragma unroll
        for (int r = 0; r < 4; r++) {
          float v = acc[i][j][r];
          if (BIAS) v += bv_[j];
          if (ACT == 1) v = geluf(v);
          else if (ACT == 2) v = eluf(v);
          epi[(i * 16 + fg * 4 + r) * 64 + j * 16 + fr] = f2bf(v);
        }
    #pragma unroll
    for (int it = 0; it < 16; it++) {
      int lrow = it * 8 + (lane >> 3);
      int grow = m0 + wm + lrow;
      int gcol = n0 + wn + (lane & 7) * 8;
      if (grow < M && gcol < N)
        *(short8*)(Cb + (long long)grow * ldc + gcol) =
            *(const short8*)(epi + lrow * 64 + (lane & 7) * 8);
    }
  }
}

// ---------------- 128-tile NT GEMM (small-M split-K) ----------------
template<int ACT, int BIAS, int OBF, int TROUT>
__global__ __launch_bounds__(256)
void k_gemm_nt(const bf16* __restrict__ A, const bf16* __restrict__ B,
               const float* __restrict__ bias, void* __restrict__ Cv,
               int M, int N, int K, int lda, int ldb, int ldc,
               long long sA, long long sB, long long sC, int nsplit, int ks)
{
  __shared__ __align__(16) bf16 As[3][128*32];
  __shared__ __align__(16) bf16 Bs[3][128*32];
  const int zb = blockIdx.z;
  const int b  = zb / nsplit;
  const int sl = zb - b*nsplit;
  const int kbeg = sl * ks;
  int kend = kbeg + ks; if (kend > K) kend = K;
  const int nt = (kend > kbeg) ? (kend - kbeg + 31) / 32 : 0;

  const bf16* Ab = A + (long long)b * sA;
  const bf16* Bb = B + (long long)b * sB;
  const long long cbase = (long long)b * sC;

  const int NTt = gridDim.x, MTt = gridDim.y;
  const int nwg = NTt * MTt;
  int orig = blockIdx.y * NTt + blockIdx.x;
  {
    const int q8 = nwg >> 3, r8 = nwg & 7;
    const int xcd = orig & 7, idx = orig >> 3;
    orig = (xcd < r8 ? xcd * (q8 + 1) : r8 * (q8 + 1) + (xcd - r8) * q8) + idx;
  }
  const int GM = 8;
  const int per_g = GM * NTt;
  const int g = orig / per_g, rem = orig - g * per_g;
  int gsz = MTt - g * GM; if (gsz > GM) gsz = GM;
  const int mi = g * GM + rem % gsz;
  const int ni = rem / gsz;

  const int m0 = mi * 128, n0 = ni * 128;
  const int tid = threadIdx.x, lane = tid & 63, wave = tid >> 6;
  const int wm = (wave >> 1) * 64, wn = (wave & 1) * 64;
  const int fr = lane & 15, fg = lane >> 4;
  const int fgs = fg ^ ((fr >> 1) & 3);

  f32x4 acc[4][4];
  #pragma unroll
  for (int i = 0; i < 4; i++)
    #pragma unroll
    for (int j = 0; j < 4; j++) acc[i][j] = (f32x4){0.f, 0.f, 0.f, 0.f};

  const int c0 = wave * 128 + lane;
  const int c1 = c0 + 64;
  const int rA0 = c0 >> 2, rA1 = c1 >> 2;
  const int cc0 = ((c0 & 3) ^ ((rA0 >> 1) & 3)) * 8;
  const int cc1 = ((c1 & 3) ^ ((rA1 >> 1) & 3)) * 8;
  int gra0 = m0 + rA0; if (gra0 >= M) gra0 = M - 1;
  int gra1 = m0 + rA1; if (gra1 >= M) gra1 = M - 1;
  int grb0 = n0 + rA0; if (grb0 >= N) grb0 = N - 1;
  int grb1 = n0 + rA1; if (grb1 >= N) grb1 = N - 1;
  const bf16* pa0 = Ab + (long long)gra0 * lda + cc0;
  const bf16* pa1 = Ab + (long long)gra1 * lda + cc1;
  const bf16* pb0 = Bb + (long long)grb0 * ldb + cc0;
  const bf16* pb1 = Bb + (long long)grb1 * ldb + cc1;

  char* lA = (char*)&As[0][0] + wave * 2048;
  char* lB = (char*)&Bs[0][0] + wave * 2048;

  #define STAGE(buf, kk) do {                       \
    char* a_ = lA + (buf) * 8192;                   \
    char* b_ = lB + (buf) * 8192;                   \
    gload16(pa0 + (kk), a_);                        \
    gload16(pa1 + (kk), a_ + 1024);                 \
    gload16(pb0 + (kk), b_);                        \
    gload16(pb1 + (kk), b_ + 1024);                 \
  } while (0)

  if (nt > 0) STAGE(0, kbeg);
  if (nt > 1) STAGE(1, kbeg + 32);

  int cur = 0;
  for (int t = 0; t < nt; t++) {
    if (t + 2 < nt) {
      int n2 = cur + 2; if (n2 >= 3) n2 -= 3;
      STAGE(n2, kbeg + (t + 2) * 32);
      asm volatile("s_waitcnt vmcnt(8)" ::: "memory");
    } else if (t + 1 < nt) {
      asm volatile("s_waitcnt vmcnt(4)" ::: "memory");
    } else {
      asm volatile("s_waitcnt vmcnt(0)" ::: "memory");
    }
    __builtin_amdgcn_s_barrier();

    const bf16* Asb = (const bf16*)((const char*)&As[0][0] + cur * 8192);
    const bf16* Bsb = (const bf16*)((const char*)&Bs[0][0] + cur * 8192);
    short8 af[4], bfv[4];
    #pragma unroll
    for (int i = 0; i < 4; i++) {
      af[i]  = *(const short8*)(Asb + (wm + i * 16 + fr) * 32 + fgs * 8);
      bfv[i] = *(const short8*)(Bsb + (wn + i * 16 + fr) * 32 + fgs * 8);
    }
    #pragma unroll
    for (int i = 0; i < 4; i++)
      #pragma unroll
      for (int j = 0; j < 4; j++)
        acc[i][j] = __builtin_amdgcn_mfma_f32_16x16x32_bf16(af[i], bfv[j], acc[i][j], 0, 0, 0);

    asm volatile("s_waitcnt lgkmcnt(0)" ::: "memory");
    __builtin_amdgcn_s_barrier();
    cur = cur + 1; if (cur >= 3) cur = 0;
  }
  #undef STAGE

  #pragma unroll
  for (int i = 0; i < 4; i++) {
    const int r0 = m0 + wm + i * 16 + fg * 4;
    #pragma unroll
    for (int j = 0; j < 4; j++) {
      const int col = n0 + wn + j * 16 + fr;
      if (col >= N) continue;
      float bv = 0.f;
      if (BIAS) bv = bias[col];
      #pragma unroll
      for (int r = 0; r < 4; r++) {
        const int row = r0 + r;
        if (row >= M) continue;
        float v = acc[i][j][r] + bv;
        if (ACT == 1) v = geluf(v);
        else if (ACT == 2) v = eluf(v);
        long long off;
        if (TROUT) off = cbase + (long long)col * ldc + row;
        else       off = cbase + (long long)row * ldc + col;
        if (OBF == 1)      ((bf16*)Cv)[off] = f2bf(v);
        else if (OBF == 2) atomicAdd(&((float*)Cv)[off], v);
        else               ((float*)Cv)[off] = v;
      }
    }
  }
}

// ---------------- small utility kernels ----------------
__global__ void k_zero(float* p, long long n) {
  long long i = (long long)blockIdx.x * blockDim.x + threadIdx.x;
  long long st = (long long)gridDim.x * blockDim.x;
  for (; i < n; i += st) p[i] = 0.f;
}

__global__ void k_f2bf(const float* __restrict__ in, bf16* __restrict__ out, long long n) {
  long long i = (long long)blockIdx.x * 256 + threadIdx.x;
  if (i < n) out[i] = f2bf(in[i]);
}

__global__ void k_cat2(const float* __restrict__ a, const float* __restrict__ b,
                       float* __restrict__ o, int na, int nb) {
  int i = blockIdx.x * 256 + threadIdx.x;
  if (i < na) o[i] = a[i];
  else if (i < na + nb) o[i] = b[i - na];
}

__global__ void k_add_emb(const float* __restrict__ x, const float* __restrict__ ns,
                          bf16* __restrict__ h0, long long n4) {
  long long i = (long long)blockIdx.x * 256 + threadIdx.x;
  long long st = (long long)gridDim.x * 256;
  for (; i < n4; i += st) {
    float4 v = ((const float4*)x)[i];
    int d = (int)(i % (DE / 4)) * 4;
    short4_t o;
    o.x = bfbits(v.x + ns[d]);
    o.y = bfbits(v.y + ns[d + 1]);
    o.z = bfbits(v.z + ns[d + 2]);
    o.w = bfbits(v.w + ns[d + 3]);
    ((short4_t*)h0)[i] = o;
  }
}

// transpose f32 [R,C] -> bf16 [C,R]; R,C multiples of 32
__global__ void k_transpose_bf(const float* __restrict__ W, bf16* __restrict__ Wt, int R, int C) {
  __shared__ float t[32][33];
  int c0 = blockIdx.x * 32, r0 = blockIdx.y * 32;
  int x = threadIdx.x, y = threadIdx.y;
  #pragma unroll
  for (int j = 0; j < 32; j += 8)
    t[y + j][x] = W[(long long)(r0 + y + j) * C + c0 + x];
  __syncthreads();
  #pragma unroll
  for (int j = 0; j < 32; j += 8)
    Wt[(long long)(c0 + y + j) * R + r0 + x] = f2bf(t[x][y + j]);
}

// es/ed per node: block = 512 threads, wave w = head
__global__ __launch_bounds__(512)
void k_esed(const bf16* __restrict__ hh, const float* __restrict__ asrc,
            const float* __restrict__ adst, float* __restrict__ es, float* __restrict__ ed) {
  int n = blockIdx.x;
  int h = threadIdx.x >> 6;
  int c = threadIdx.x & 63;
  float v = bf2f(hh[(long long)n * HD + h * 64 + c]);
  float s = v * asrc[h * 64 + c];
  float d = v * adst[h * 64 + c];
  #pragma unroll
  for (int o = 32; o; o >>= 1) { s += __shfl_down(s, o, 64); d += __shfl_down(d, o, 64); }
  if (c == 0) { es[n * 8 + h] = s; ed[n * 8 + h] = d; }
}

__global__ void k_edge_logits(const int* __restrict__ ei, int E, int TOT,
                              const float* __restrict__ es, const float* __restrict__ ed,
                              float* __restrict__ logits, unsigned* __restrict__ mkey) {
  int e = blockIdx.x * 256 + threadIdx.x;
  if (e >= TOT) return;
  int s, d;
  if (e < E) { s = ei[e]; d = ei[E + e]; } else { s = d = e - E; }
  #pragma unroll
  for (int h = 0; h < 8; h++) {
    float l = es[s * 8 + h] + ed[d * 8 + h];
    l = l > 0.f ? l : 0.2f * l;
    logits[(long long)e * 8 + h] = l;
    unsigned u = __float_as_uint(l);
    unsigned key = (u & 0x80000000u) ? ~u : (u | 0x80000000u);
    atomicMax(&mkey[d * 8 + h], key);
  }
}

__global__ void k_edge_exp(const int* __restrict__ ei, int E, int TOT,
                           const unsigned* __restrict__ mkey, float* __restrict__ logits,
                           float* __restrict__ den) {
  int e = blockIdx.x * 256 + threadIdx.x;
  if (e >= TOT) return;
  int d = (e < E) ? ei[E + e] : (e - E);
  #pragma unroll
  for (int h = 0; h < 8; h++) {
    unsigned key = mkey[d * 8 + h];
    unsigned u = (key & 0x80000000u) ? (key & 0x7fffffffu) : ~key;
    float m = __uint_as_float(u);
    float ex = expf(logits[(long long)e * 8 + h] - m);
    logits[(long long)e * 8 + h] = ex;
    atomicAdd(&den[d * 8 + h], ex);
  }
}

__global__ __launch_bounds__(256)
void k_edge_aggr(const int* __restrict__ ei, int E, int TOT,
                 const float* __restrict__ logits, const float* __restrict__ den,
                 const bf16* __restrict__ hh, float* __restrict__ accum) {
  int base = blockIdx.x * 4;
  for (int u = 0; u < 4; u++) {
    int e = base + u;
    if (e >= TOT) break;
    int s, d;
    if (e < E) { s = ei[e]; d = ei[E + e]; } else { s = d = e - E; }
    #pragma unroll
    for (int half = 0; half < 2; half++) {
      int idx = threadIdx.x + half * 256;
      int h = idx >> 6;
      float alpha = logits[(long long)e * 8 + h] / (den[d * 8 + h] + 1e-16f);
      float v = bf2f(hh[(long long)s * HD + idx]) * alpha;
      atomicAdd(&accum[(long long)d * HD + idx], v);
    }
  }
}

template<int ACT>
__global__ void k_gat_fin(const float* __restrict__ accum, const float* __restrict__ b,
                          bf16* __restrict__ out) {
  int i = blockIdx.x * 256 + threadIdx.x;
  long long n = blockIdx.y;
  float v = accum[n * HD + i] + b[i];
  if (ACT == 2) v = eluf(v);
  out[n * HD + i] = f2bf(v);
}

template<int ACT, int BIAS, int TOBF>
__global__ void k_postproc(float* __restrict__ acc, const float* __restrict__ bias,
                           bf16* __restrict__ obf, long long tot, int cols) {
  long long i = (long long)blockIdx.x * 256 + threadIdx.x;
  if (i >= tot) return;
  int c = (int)(i % cols);
  float v = acc[i];
  if (BIAS) v += bias[c];
  if (ACT == 1) v = geluf(v);
  if (TOBF) obf[i] = f2bf(v);
  else acc[i] = v;
}

// row softmax (in-place capable): scores bf16 [rows][NPAD], scale folded
__global__ __launch_bounds__(256)
void k_softmax_row(const bf16* s_all, bf16* a_all, int NV) {
  long long row = blockIdx.x;
  const bf16* s = s_all + row * NPAD;
  bf16* a = a_all + row * NPAD;
  int tid = threadIdx.x;
  __shared__ float red[4];
  float mx = -3.0e38f;
  for (int c = tid; c < NV; c += 256) mx = fmaxf(mx, bf2f(s[c]));
  #pragma unroll
  for (int o = 32; o; o >>= 1) mx = fmaxf(mx, __shfl_down(mx, o, 64));
  if ((tid & 63) == 0) red[tid >> 6] = mx;
  __syncthreads();
  mx = fmaxf(fmaxf(red[0], red[1]), fmaxf(red[2], red[3]));
  const float inv = 0.05590169943749474f;  // 1/sqrt(320)
  float sm = 0.f;
  for (int c = tid; c < NV; c += 256) sm += expf((bf2f(s[c]) - mx) * inv);
  #pragma unroll
  for (int o = 32; o; o >>= 1) sm += __shfl_down(sm, o, 64);
  __syncthreads();
  if ((tid & 63) == 0) red[tid >> 6] = sm;
  __syncthreads();
  sm = red[0] + red[1] + red[2] + red[3];
  float rs = 1.f / sm;
  for (int c = tid; c < NPAD; c += 256) {
    float v = (c < NV) ? expf((bf2f(s[c]) - mx) * inv) * rs : 0.f;
    a[c] = f2bf(v);
  }
}

// LayerNorm(a+b) row of DE, optional bf16 dup
template<int WB>
__global__ __launch_bounds__(256)
void k_ln(const float* __restrict__ a, const float* __restrict__ b,
          const float* __restrict__ g, const float* __restrict__ bt,
          float* __restrict__ out, bf16* __restrict__ obf) {
  long long row = blockIdx.x;
  __shared__ float xs[DE];
  __shared__ float red[4];
  int tid = threadIdx.x;
  float sum = 0.f;
  for (int c = tid; c < DE; c += 256) {
    float v = a[row * DE + c] + b[row * DE + c];
    xs[c] = v; sum += v;
  }
  #pragma unroll
  for (int o = 32; o; o >>= 1) sum += __shfl_down(sum, o, 64);
  if ((tid & 63) == 0) red[tid >> 6] = sum;
  __syncthreads();
  float mean = (red[0] + red[1] + red[2] + red[3]) * (1.f / DE);
  float vs = 0.f;
  for (int c = tid; c < DE; c += 256) { float t = xs[c] - mean; vs += t * t; }
  #pragma unroll
  for (int o = 32; o; o >>= 1) vs += __shfl_down(vs, o, 64);
  __syncthreads();
  if ((tid & 63) == 0) red[tid >> 6] = vs;
  __syncthreads();
  float var = (red[0] + red[1] + red[2] + red[3]) * (1.f / DE);
  float sc = rsqrtf(var + 1e-5f);
  for (int c = tid; c < DE; c += 256) {
    float v = (xs[c] - mean) * sc * g[c] + bt[c];
    out[row * DE + c] = v;
    if (WB) obf[row * DE + c] = f2bf(v);
  }
}

// ---------------- host ----------------
extern "C" void kernel_launch(void* const* d_in, const int* in_sizes, int n_in,
                              void* d_out, int out_size, void* d_ws, size_t ws_size,
                              hipStream_t stream)
{
  const float* x       = (const float*)d_in[0];
  const int*   ei      = (const int*)d_in[1];
  const float* ns_emb  = (const float*)d_in[2];
  const float* gat_w0  = (const float*)d_in[3];
  const float* gat_wr  = (const float*)d_in[4];
  const float* a_src   = (const float*)d_in[5];
  const float* a_dst   = (const float*)d_in[6];
  const float* gat_b   = (const float*)d_in[7];
  const float* proj_w1 = (const float*)d_in[8];
  const float* proj_b1 = (const float*)d_in[9];
  const float* proj_w2 = (const float*)d_in[10];
  const float* proj_b2 = (const float*)d_in[11];
  const float* queries = (const float*)d_in[12];
  const float* wq = (const float*)d_in[13]; const float* bq = (const float*)d_in[14];
  const float* wk = (const float*)d_in[15]; const float* bk = (const float*)d_in[16];
  const float* wv = (const float*)d_in[17]; const float* bv = (const float*)d_in[18];
  const float* wo = (const float*)d_in[19]; const float* bo = (const float*)d_in[20];
  const float* ln1g = (const float*)d_in[21]; const float* ln1b = (const float*)d_in[22];
  const float* fw1 = (const float*)d_in[23]; const float* fb1 = (const float*)d_in[24];
  const float* fw2 = (const float*)d_in[25]; const float* fb2 = (const float*)d_in[26];
  const float* ln2g = (const float*)d_in[27]; const float* ln2b = (const float*)d_in[28];
  float* out = (float*)d_out;

  const int N = in_sizes[0] / DE;   // 30000
  const int E = in_sizes[1] / 2;    // 90000
  const int TOT = E + N;            // 120000
  const int MT2 = (N + 255) / 256;  // 256-tile M count (118)

  char* base = (char*)d_ws;
  size_t off = 0;
  auto AL = [&](size_t bytes) -> void* {
    void* p = base + off;
    off += (bytes + 255) & ~(size_t)255;
    return p;
  };
  bf16* wt_g0 = (bf16*)AL((size_t)HD * DE * 2);
  bf16* wt_g1 = (bf16*)AL((size_t)HD * HD * 2);
  bf16* wt_g2 = (bf16*)AL((size_t)HD * HD * 2);
  bf16* wt_p1 = (bf16*)AL((size_t)HD * HD * 2);
  bf16* wt_p2 = (bf16*)AL((size_t)DE * HD * 2);
  bf16* wt_q  = (bf16*)AL((size_t)DE * DE * 2);
  bf16* wt_kv = (bf16*)AL((size_t)2 * DE * DE * 2);   // [5120][2560]
  bf16* wt_o  = (bf16*)AL((size_t)DE * DE * 2);
  bf16* wt_f1 = (bf16*)AL((size_t)4 * DE * DE * 2);
  bf16* wt_f2 = (bf16*)AL((size_t)4 * DE * DE * 2);
  float* bias_kv = (float*)AL((size_t)2 * DE * 4);
  bf16* big0  = (bf16*)AL((size_t)N * DE * 2);      // h0 -> hD
  bf16* big1  = (bf16*)AL((size_t)N * DE * 2);      // k
  bf16* vT    = (bf16*)AL((size_t)DE * NPAD * 2);
  // GAT scratch block (contiguous; overlaid by `sc` in attention phase)
  bf16* hhA   = (bf16*)AL((size_t)N * HD * 2);
  bf16* hB    = (bf16*)AL((size_t)N * HD * 2);
  float* accum  = (float*)AL((size_t)N * HD * 4);
  float* logits = (float*)AL((size_t)TOT * 8 * 4);
  unsigned* mkey = (unsigned*)AL((size_t)N * 8 * 4);
  float* den = (float*)AL((size_t)N * 8 * 4);
  float* es  = (float*)AL((size_t)N * 8 * 4);
  float* edv = (float*)AL((size_t)N * 8 * 4);
  bf16* sc = (bf16*)hhA;  // scores/attn [8][QNUM][NPAD] bf16 = 96MB < 130MB block
  // small f32 pool (zeroed once; targets of split-K atomic GEMMs)
  float* q_f     = (float*)AL((size_t)QNUM * DE * 4);
  float* ctx_f   = (float*)AL((size_t)QNUM * DE * 4);
  float* attnout = (float*)AL((size_t)QNUM * DE * 4);
  float* f1_f    = (float*)AL((size_t)QNUM * 4 * DE * 4);
  float* f2_f    = (float*)AL((size_t)QNUM * DE * 4);
  bf16* qs_bf  = (bf16*)AL((size_t)QNUM * DE * 2);
  bf16* q_bf   = (bf16*)AL((size_t)QNUM * DE * 2);
  bf16* ctx_bf = (bf16*)AL((size_t)QNUM * DE * 2);
  float* attended = (float*)AL((size_t)QNUM * DE * 4);
  bf16* att_bf = (bf16*)AL((size_t)QNUM * DE * 2);
  bf16* f1_bf  = (bf16*)AL((size_t)QNUM * 4 * DE * 2);

  dim3 blk(256);
  dim3 tblk(32, 8);

  // weight convert+transpose to bf16 [out,in]
  k_transpose_bf<<<dim3(HD / 32, DE / 32), tblk, 0, stream>>>(gat_w0, wt_g0, DE, HD);
  k_transpose_bf<<<dim3(HD / 32, HD / 32), tblk, 0, stream>>>(gat_wr, wt_g1, HD, HD);
  k_transpose_bf<<<dim3(HD / 32, HD / 32), tblk, 0, stream>>>(gat_wr + (size_t)HD * HD, wt_g2, HD, HD);
  k_transpose_bf<<<dim3(HD / 32, HD / 32), tblk, 0, stream>>>(proj_w1, wt_p1, HD, HD);
  k_transpose_bf<<<dim3(DE / 32, HD / 32), tblk, 0, stream>>>(proj_w2, wt_p2, HD, DE);
  k_transpose_bf<<<dim3(DE / 32, DE / 32), tblk, 0, stream>>>(wq, wt_q, DE, DE);
  k_transpose_bf<<<dim3(DE / 32, DE / 32), tblk, 0, stream>>>(wk, wt_kv, DE, DE);
  k_transpose_bf<<<dim3(DE / 32, DE / 32), tblk, 0, stream>>>(wv, wt_kv + (size_t)DE * DE, DE, DE);
  k_transpose_bf<<<dim3(DE / 32, DE / 32), tblk, 0, stream>>>(wo, wt_o, DE, DE);
  k_transpose_bf<<<dim3(4 * DE / 32, DE / 32), tblk, 0, stream>>>(fw1, wt_f1, DE, 4 * DE);
  k_transpose_bf<<<dim3(DE / 32, 4 * DE / 32), tblk, 0, stream>>>(fw2, wt_f2, 4 * DE, DE);
  k_cat2<<<dim3((2 * DE + 255) / 256), blk, 0, stream>>>(bk, bv, bias_kv, DE, DE);

  k_add_emb<<<dim3(2048), blk, 0, stream>>>(x, ns_emb, big0, (long long)N * DE / 4);
  k_f2bf<<<dim3((QNUM * DE + 255) / 256), blk, 0, stream>>>(queries, qs_bf, (long long)QNUM * DE);
  {
    long long pool = (long long)QNUM * DE * 4 + (long long)QNUM * 4 * DE;
    k_zero<<<dim3(1024), blk, 0, stream>>>(q_f, pool);
  }

  // ---- GAT layers ----
  const bf16* gw[3] = { wt_g0, wt_g1, wt_g2 };
  const long long zcnt = (long long)N * HD + (long long)TOT * 8 + (long long)N * 16;
  for (int l = 0; l < 3; l++) {
    const bf16* Ain = (l == 0) ? big0 : hB;
    int Kd = (l == 0) ? DE : HD;
    k_gemm256<0,0,0><<<dim3(2, MT2), dim3(512), 0, stream>>>(Ain, gw[l], nullptr, hhA,
        nullptr, 0, N, HD, HD, Kd, Kd, Kd, HD, 0, 0, 0);
    k_zero<<<dim3(2048), blk, 0, stream>>>(accum, zcnt);
    k_esed<<<dim3(N), dim3(512), 0, stream>>>(hhA, a_src + l * HD, a_dst + l * HD, es, edv);
    k_edge_logits<<<dim3((TOT + 255) / 256), blk, 0, stream>>>(ei, E, TOT, es, edv, logits, mkey);
    k_edge_exp<<<dim3((TOT + 255) / 256), blk, 0, stream>>>(ei, E, TOT, mkey, logits, den);
    k_edge_aggr<<<dim3((TOT + 3) / 4), blk, 0, stream>>>(ei, E, TOT, logits, den, hhA, accum);
    if (l < 2) k_gat_fin<2><<<dim3(2, N), blk, 0, stream>>>(accum, gat_b + l * HD, hB);
    else       k_gat_fin<0><<<dim3(2, N), blk, 0, stream>>>(accum, gat_b + l * HD, hB);
  }

  // ---- projection ----
  k_gemm256<1,1,0><<<dim3(2, MT2), dim3(512), 0, stream>>>(hB, wt_p1, proj_b1, hhA,
      nullptr, 0, N, HD, HD, HD, HD, HD, HD, 0, 0, 0);
  k_gemm256<0,1,0><<<dim3(10, MT2), dim3(512), 0, stream>>>(hhA, wt_p2, proj_b2, big0,
      nullptr, 0, N, DE, DE, HD, HD, HD, DE, 0, 0, 0);

  // ---- q (split-K), fused k+v (k -> big1 normal, v -> vT transposed) ----
  k_gemm_nt<0,0,2,0><<<dim3(20, 2, 8), blk, 0, stream>>>(qs_bf, wt_q, nullptr, q_f,
      QNUM, DE, DE, DE, DE, DE, 0, 0, 0, 8, 320);
  k_postproc<0,1,1><<<dim3((QNUM * DE + 255) / 256), blk, 0, stream>>>(q_f, bq, q_bf,
      (long long)QNUM * DE, DE);
  k_gemm256<0,1,1><<<dim3(20, MT2), dim3(512), 0, stream>>>(big0, wt_kv, bias_kv, big1,
      vT, DE, N, 2 * DE, 2 * DE, DE, DE, DE, DE, 0, 0, 0);

  // ---- scores, softmax, ctx (split-K 32) ----
  k_gemm256<0,0,0><<<dim3((NPAD + 255) / 256, 1, 8), dim3(512), 0, stream>>>(q_bf, big1, nullptr, sc,
      nullptr, 0, QNUM, NPAD, N, ADHD, DE, DE, NPAD, 320, 320, (long long)QNUM * NPAD);
  k_softmax_row<<<dim3(8 * QNUM), blk, 0, stream>>>(sc, sc, N);
  k_gemm_nt<0,0,2,0><<<dim3(3, 2, 8 * 32), blk, 0, stream>>>(sc, vT, nullptr, ctx_f,
      QNUM, ADHD, NPAD, NPAD, NPAD, DE, (long long)QNUM * NPAD, (long long)ADHD * NPAD, 320, 32, 960);
  k_postproc<0,0,1><<<dim3((QNUM * DE + 255) / 256), blk, 0, stream>>>(ctx_f, nullptr, ctx_bf,
      (long long)QNUM * DE, DE);

  // ---- output projection + LN1 ----
  k_gemm_nt<0,0,2,0><<<dim3(20, 2, 8), blk, 0, stream>>>(ctx_bf, wt_o, nullptr, attnout,
      QNUM, DE, DE, DE, DE, DE, 0, 0, 0, 8, 320);
  k_postproc<0,1,0><<<dim3((QNUM * DE + 255) / 256), blk, 0, stream>>>(attnout, bo, nullptr,
      (long long)QNUM * DE, DE);
  k_ln<1><<<dim3(QNUM), blk, 0, stream>>>(queries, attnout, ln1g, ln1b, attended, att_bf);

  // ---- FFN + LN2 ----
  k_gemm_nt<0,0,2,0><<<dim3(80, 2, 4), blk, 0, stream>>>(att_bf, wt_f1, nullptr, f1_f,
      QNUM, 4 * DE, DE, DE, DE, 4 * DE, 0, 0, 0, 4, 640);
  k_postproc<1,1,1><<<dim3((QNUM * 4 * DE + 255) / 256), blk, 0, stream>>>(f1_f, fb1, f1_bf,
      (long long)QNUM * 4 * DE, 4 * DE);
  k_gemm_nt<0,0,2,0><<<dim3(20, 2, 8), blk, 0, stream>>>(f1_bf, wt_f2, nullptr, f2_f,
      QNUM, DE, 4 * DE, 4 * DE, 4 * DE, DE, 0, 0, 0, 8, 1280);
  k_postproc<0,1,0><<<dim3((QNUM * DE + 255) / 256), blk, 0, stream>>>(f2_f, fb2, nullptr,
      (long long)QNUM * DE, DE);
  k_ln<0><<<dim3(QNUM), blk, 0, stream>>>(attended, f2_f, ln2g, ln2b, out, nullptr);
}

// Round 5
// 1884.706 us; speedup vs baseline: 1.9096x; 1.4111x over previous
//
#include <hip/hip_runtime.h>
#include <hip/hip_bf16.h>
#include <cmath>

typedef __hip_bfloat16 bf16;
typedef __attribute__((ext_vector_type(8))) short short8;
typedef __attribute__((ext_vector_type(4))) short short4_t;
typedef __attribute__((ext_vector_type(4))) float f32x4;
typedef __attribute__((address_space(1))) void as1_void;
typedef __attribute__((address_space(3))) void as3_void;

#define DE   2560
#define HD   512
#define NPAD 30016
#define QNUM 200
#define ADHD 320

static __device__ __forceinline__ float bf2f(bf16 v){ return __bfloat162float(v); }
static __device__ __forceinline__ bf16  f2bf(float v){ return __float2bfloat16(v); }
static __device__ __forceinline__ short bfbits(float f){ bf16 b = f2bf(f); return *reinterpret_cast<short*>(&b); }
static __device__ __forceinline__ float geluf(float x){ return 0.5f*x*(1.0f+erff(x*0.70710678118654752440f)); }
static __device__ __forceinline__ float eluf(float x){ return x>0.f ? x : expm1f(x); }

static __device__ __forceinline__ void gload16(const void* g, void* l){
  __builtin_amdgcn_global_load_lds((as1_void*)g, (as3_void*)l, 16, 0, 0);
}

// =================== 256x256 8-phase bf16 NT GEMM ===================
// C[M,N](bf16) = act(A[M,K] * B[N,K]^T + bias). BK=64, 512 thr (8 waves 2Mx4N),
// 128KB LDS dbuf. Quadrant order (0,0)->(0,1)->(1,1)->(1,0): each phase reloads
// only the CHANGED operand half. Counted vmcnt (never 0 mid-loop), one granule
// staged per phase for tile t+1 in need-order A0,B0,B1,A1. LDS chunk swizzle on
// both source and read. gm = M-supertile height (runtime).
// KV mode: cols >= NK stored TRANSPOSED into C2 ([col][NPAD], pad rows zeroed).
template<int ACT, int BIAS, int KV>
__global__ __launch_bounds__(512, 1)
void k_gemm256(const bf16* __restrict__ A, const bf16* __restrict__ B,
               const float* __restrict__ bias, bf16* __restrict__ C,
               bf16* __restrict__ C2, int NK, int gm,
               int M, int N, int NB, int K, int lda, int ldb, int ldc,
               long long sA, long long sB, long long sC)
{
  __shared__ __align__(16) char smem[131072];   // A:[2][32KB] @0, B:[2][32KB] @64KB
  const int bz = blockIdx.z;
  const bf16* Ab = A + (long long)bz * sA;
  const bf16* Bb = B + (long long)bz * sB;
  bf16* Cb = C + (long long)bz * sC;

  // block swizzle: XCD-bijective then gm-supertile over M
  const int gx = gridDim.x, gy = gridDim.y;
  const int nwg = gx * gy;
  int orig = blockIdx.y * gx + blockIdx.x;
  {
    const int q8 = nwg >> 3, r8 = nwg & 7;
    const int xcd = orig & 7, idx = orig >> 3;
    orig = (xcd < r8 ? xcd * (q8 + 1) : r8 * (q8 + 1) + (xcd - r8) * q8) + idx;
  }
  const int per_g = gm * gx;
  const int g = orig / per_g, rem = orig - g * per_g;
  int gsz = gy - g * gm; if (gsz > gm) gsz = gm;
  const int mi = g * gm + rem % gsz;
  const int ni = rem / gsz;
  const int m0 = mi * 256, n0 = ni * 256;

  const int tid = threadIdx.x, lane = tid & 63, wave = tid >> 6;
  const int wm = (wave >> 2) * 128, wn = (wave & 3) * 64;
  const int fr = lane & 15, fg = lane >> 4;
  const int cS0 = ((fg) ^ (fr & 7)) * 16;        // swizzled byte off, ksub 0
  const int cS1 = ((4 + fg) ^ (fr & 7)) * 16;    // ksub 1

  // stage source pointers (per lane): granule = half-operand (128 rows x 64)
  const bf16* pA[2][2]; const bf16* pB[2][2];
  #pragma unroll
  for (int L = 0; L < 2; L++) {
    const int ch = L * 512 + tid;
    const int lr = ch >> 3;
    #pragma unroll
    for (int mh = 0; mh < 2; mh++) {
      int r = (lr & 63) + mh * 64 + ((lr & 64) << 1);
      int cs = (ch & 7) ^ (r & 7);
      int gr = m0 + r; if (gr > M - 1) gr = M - 1;
      pA[mh][L] = Ab + (long long)gr * lda + cs * 8;
    }
    #pragma unroll
    for (int nh = 0; nh < 2; nh++) {
      int r = nh * 32 + (lr & 31) + ((lr >> 5) << 6);
      int cs = (ch & 7) ^ (r & 7);
      int gr = n0 + r; if (gr > NB - 1) gr = NB - 1;
      pB[nh][L] = Bb + (long long)gr * ldb + cs * 8;
    }
  }

  #define STG_A(mh, buf, kk) do {                                        \
    char* d_ = smem + (buf) * 32768 + ((mh) * 64 + wave * 8) * 128;      \
    gload16(pA[mh][0] + (kk), d_);                                       \
    gload16(pA[mh][1] + (kk), d_ + 16384);                               \
  } while (0)
  #define STG_B(nh, buf, kk) do {                                        \
    char* d_ = smem + 65536 + (buf) * 32768 +                            \
               ((nh) * 32 + (wave & 3) * 8 + (wave >> 2) * 64) * 128;    \
    gload16(pB[nh][0] + (kk), d_);                                       \
    gload16(pB[nh][1] + (kk), d_ + 16384);                               \
  } while (0)

  f32x4 acc[8][4];
  #pragma unroll
  for (int i = 0; i < 8; i++)
    #pragma unroll
    for (int j = 0; j < 4; j++) acc[i][j] = (f32x4){0.f, 0.f, 0.f, 0.f};

  const int nt = K / 64;
  // prologue: tile 0 -> buf 0, granule NEED-order A0,B0,B1,A1
  STG_A(0, 0, 0); STG_B(0, 0, 0); STG_B(1, 0, 0); STG_A(1, 0, 0);

  #define LOAD_A(mh) do {                                                \
    _Pragma("unroll")                                                    \
    for (int i = 0; i < 4; i++) {                                        \
      const char* p_ = Ab_l + (wm + (mh) * 64 + i * 16 + fr) * 128;      \
      a_[i][0] = *(const short8*)(p_ + cS0);                             \
      a_[i][1] = *(const short8*)(p_ + cS1);                             \
    }                                                                    \
  } while (0)
  #define LOAD_B(nh) do {                                                \
    _Pragma("unroll")                                                    \
    for (int j = 0; j < 2; j++) {                                        \
      const char* p_ = Bb_l + (wn + (nh) * 32 + j * 16 + fr) * 128;      \
      b_[j][0] = *(const short8*)(p_ + cS0);                             \
      b_[j][1] = *(const short8*)(p_ + cS1);                             \
    }                                                                    \
  } while (0)
  #define MFMA_Q(mh, nh) do {                                            \
    __builtin_amdgcn_s_setprio(1);                                       \
    _Pragma("unroll")                                                    \
    for (int i = 0; i < 4; i++)                                          \
      _Pragma("unroll")                                                  \
      for (int j = 0; j < 2; j++) {                                      \
        acc[(mh)*4+i][(nh)*2+j] = __builtin_amdgcn_mfma_f32_16x16x32_bf16( \
            a_[i][0], b_[j][0], acc[(mh)*4+i][(nh)*2+j], 0, 0, 0);       \
        acc[(mh)*4+i][(nh)*2+j] = __builtin_amdgcn_mfma_f32_16x16x32_bf16( \
            a_[i][1], b_[j][1], acc[(mh)*4+i][(nh)*2+j], 0, 0, 0);       \
      }                                                                  \
    __builtin_amdgcn_s_setprio(0);                                       \
  } while (0)

  for (int t = 0; t < nt; ++t) {
    const int buf = t & 1, nb = buf ^ 1;
    const int kn = (t + 1) * 64;
    const bool pf = (t + 1 < nt);
    const char* Ab_l = smem + buf * 32768;
    const char* Bb_l = smem + 65536 + buf * 32768;
    short8 a_[4][2], b_[2][2];

    // ph0: quadrant (0,0) — needs A0,B0
    asm volatile("s_waitcnt vmcnt(4)" ::: "memory");
    __builtin_amdgcn_s_barrier();
    LOAD_A(0); LOAD_B(0);
    if (pf) STG_A(0, nb, kn);
    MFMA_Q(0, 0);

    // ph1: quadrant (0,1) — reuse a_, needs B1
    if (pf) { asm volatile("s_waitcnt vmcnt(4)" ::: "memory"); }
    else    { asm volatile("s_waitcnt vmcnt(2)" ::: "memory"); }
    __builtin_amdgcn_s_barrier();
    LOAD_B(1);
    if (pf) STG_B(0, nb, kn);
    MFMA_Q(0, 1);

    // ph2: quadrant (1,1) — reuse b_, needs A1
    if (pf) { asm volatile("s_waitcnt vmcnt(4)" ::: "memory"); }
    else    { asm volatile("s_waitcnt vmcnt(0)" ::: "memory"); }
    __builtin_amdgcn_s_barrier();
    LOAD_A(1);
    if (pf) STG_B(1, nb, kn);
    MFMA_Q(1, 1);

    // ph3: quadrant (1,0) — reuse a_, re-read B0 (long landed)
    __builtin_amdgcn_s_barrier();
    LOAD_B(0);
    if (pf) STG_A(1, nb, kn);
    MFMA_Q(1, 0);
  }
  #undef LOAD_A
  #undef LOAD_B
  #undef MFMA_Q
  #undef STG_A
  #undef STG_B

  // ---- epilogue ----
  asm volatile("s_waitcnt vmcnt(0)" ::: "memory");
  __builtin_amdgcn_s_barrier();
  float bv_[4];
  #pragma unroll
  for (int j = 0; j < 4; j++) {
    int c = n0 + wn + j * 16 + fr;
    bv_[j] = (BIAS && c < N) ? bias[c] : 0.f;
  }

  if (KV && n0 >= NK) {
    // transposed store into C2[col'][NPAD], col' = global col - NK; pad rows zeroed
    bf16* epi = (bf16*)(smem + wave * 16384);   // [64 cols][128 rows], row-XOR swz
    #pragma unroll
    for (int i = 0; i < 8; i++)
      #pragma unroll
      for (int j = 0; j < 4; j++)
        #pragma unroll
        for (int r = 0; r < 4; r++) {
          int row = i * 16 + fg * 4 + r;
          int col = j * 16 + fr;
          float v = acc[i][j][r];
          if (BIAS) v += bv_[j];
          if (ACT == 1) v = geluf(v);
          else if (ACT == 2) v = eluf(v);
          if (m0 + wm + row >= M) v = 0.f;
          epi[col * 128 + (row ^ ((col & 7) << 3))] = f2bf(v);
        }
    #pragma unroll
    for (int it = 0; it < 16; it++) {
      int col = it * 4 + (lane >> 4);
      int row0 = (lane & 15) * 8;
      int grow = m0 + wm + row0;
      int gcol = n0 - NK + wn + col;
      if (grow < NPAD)
        *(short8*)(C2 + (long long)gcol * NPAD + grow) =
            *(const short8*)(epi + col * 128 + (row0 ^ ((col & 7) << 3)));
    }
  } else {
    bf16* epi = (bf16*)(smem + wave * 16384);   // [128 rows][64 cols]
    #pragma unroll
    for (int i = 0; i < 8; i++)
      #pragma unroll
      for (int j = 0; j < 4; j++)
        #pragma unroll
        for (int r = 0; r < 4; r++) {
          float v = acc[i][j][r];
          if (BIAS) v += bv_[j];
          if (ACT == 1) v = geluf(v);
          else if (ACT == 2) v = eluf(v);
          epi[(i * 16 + fg * 4 + r) * 64 + j * 16 + fr] = f2bf(v);
        }
    #pragma unroll
    for (int it = 0; it < 16; it++) {
      int lrow = it * 8 + (lane >> 3);
      int grow = m0 + wm + lrow;
      int gcol = n0 + wn + (lane & 7) * 8;
      if (grow < M && gcol < N)
        *(short8*)(Cb + (long long)grow * ldc + gcol) =
            *(const short8*)(epi + lrow * 64 + (lane & 7) * 8);
    }
  }
}

// ---------------- 128-tile NT GEMM (small-M split-K) ----------------
template<int ACT, int BIAS, int OBF, int TROUT>
__global__ __launch_bounds__(256)
void k_gemm_nt(const bf16* __restrict__ A, const bf16* __restrict__ B,
               const float* __restrict__ bias, void* __restrict__ Cv,
               int M, int N, int K, int lda, int ldb, int ldc,
               long long sA, long long sB, long long sC, int nsplit, int ks)
{
  __shared__ __align__(16) bf16 As[3][128*32];
  __shared__ __align__(16) bf16 Bs[3][128*32];
  const int zb = blockIdx.z;
  const int b  = zb / nsplit;
  const int sl = zb - b*nsplit;
  const int kbeg = sl * ks;
  int kend = kbeg + ks; if (kend > K) kend = K;
  const int nt = (kend > kbeg) ? (kend - kbeg + 31) / 32 : 0;

  const bf16* Ab = A + (long long)b * sA;
  const bf16* Bb = B + (long long)b * sB;
  const long long cbase = (long long)b * sC;

  const int NTt = gridDim.x, MTt = gridDim.y;
  const int nwg = NTt * MTt;
  int orig = blockIdx.y * NTt + blockIdx.x;
  {
    const int q8 = nwg >> 3, r8 = nwg & 7;
    const int xcd = orig & 7, idx = orig >> 3;
    orig = (xcd < r8 ? xcd * (q8 + 1) : r8 * (q8 + 1) + (xcd - r8) * q8) + idx;
  }
  const int GM = 8;
  const int per_g = GM * NTt;
  const int g = orig / per_g, rem = orig - g * per_g;
  int gsz = MTt - g * GM; if (gsz > GM) gsz = GM;
  const int mi = g * GM + rem % gsz;
  const int ni = rem / gsz;

  const int m0 = mi * 128, n0 = ni * 128;
  const int tid = threadIdx.x, lane = tid & 63, wave = tid >> 6;
  const int wm = (wave >> 1) * 64, wn = (wave & 1) * 64;
  const int fr = lane & 15, fg = lane >> 4;
  const int fgs = fg ^ ((fr >> 1) & 3);

  f32x4 acc[4][4];
  #pragma unroll
  for (int i = 0; i < 4; i++)
    #pragma unroll
    for (int j = 0; j < 4; j++) acc[i][j] = (f32x4){0.f, 0.f, 0.f, 0.f};

  const int c0 = wave * 128 + lane;
  const int c1 = c0 + 64;
  const int rA0 = c0 >> 2, rA1 = c1 >> 2;
  const int cc0 = ((c0 & 3) ^ ((rA0 >> 1) & 3)) * 8;
  const int cc1 = ((c1 & 3) ^ ((rA1 >> 1) & 3)) * 8;
  int gra0 = m0 + rA0; if (gra0 >= M) gra0 = M - 1;
  int gra1 = m0 + rA1; if (gra1 >= M) gra1 = M - 1;
  int grb0 = n0 + rA0; if (grb0 >= N) grb0 = N - 1;
  int grb1 = n0 + rA1; if (grb1 >= N) grb1 = N - 1;
  const bf16* pa0 = Ab + (long long)gra0 * lda + cc0;
  const bf16* pa1 = Ab + (long long)gra1 * lda + cc1;
  const bf16* pb0 = Bb + (long long)grb0 * ldb + cc0;
  const bf16* pb1 = Bb + (long long)grb1 * ldb + cc1;

  char* lA = (char*)&As[0][0] + wave * 2048;
  char* lB = (char*)&Bs[0][0] + wave * 2048;

  #define STAGE(buf, kk) do {                       \
    char* a_ = lA + (buf) * 8192;                   \
    char* b_ = lB + (buf) * 8192;                   \
    gload16(pa0 + (kk), a_);                        \
    gload16(pa1 + (kk), a_ + 1024);                 \
    gload16(pb0 + (kk), b_);                        \
    gload16(pb1 + (kk), b_ + 1024);                 \
  } while (0)

  if (nt > 0) STAGE(0, kbeg);
  if (nt > 1) STAGE(1, kbeg + 32);

  int cur = 0;
  for (int t = 0; t < nt; t++) {
    if (t + 2 < nt) {
      int n2 = cur + 2; if (n2 >= 3) n2 -= 3;
      STAGE(n2, kbeg + (t + 2) * 32);
      asm volatile("s_waitcnt vmcnt(8)" ::: "memory");
    } else if (t + 1 < nt) {
      asm volatile("s_waitcnt vmcnt(4)" ::: "memory");
    } else {
      asm volatile("s_waitcnt vmcnt(0)" ::: "memory");
    }
    __builtin_amdgcn_s_barrier();

    const bf16* Asb = (const bf16*)((const char*)&As[0][0] + cur * 8192);
    const bf16* Bsb = (const bf16*)((const char*)&Bs[0][0] + cur * 8192);
    short8 af[4], bfv[4];
    #pragma unroll
    for (int i = 0; i < 4; i++) {
      af[i]  = *(const short8*)(Asb + (wm + i * 16 + fr) * 32 + fgs * 8);
      bfv[i] = *(const short8*)(Bsb + (wn + i * 16 + fr) * 32 + fgs * 8);
    }
    #pragma unroll
    for (int i = 0; i < 4; i++)
      #pragma unroll
      for (int j = 0; j < 4; j++)
        acc[i][j] = __builtin_amdgcn_mfma_f32_16x16x32_bf16(af[i], bfv[j], acc[i][j], 0, 0, 0);

    asm volatile("s_waitcnt lgkmcnt(0)" ::: "memory");
    __builtin_amdgcn_s_barrier();
    cur = cur + 1; if (cur >= 3) cur = 0;
  }
  #undef STAGE

  #pragma unroll
  for (int i = 0; i < 4; i++) {
    const int r0 = m0 + wm + i * 16 + fg * 4;
    #pragma unroll
    for (int j = 0; j < 4; j++) {
      const int col = n0 + wn + j * 16 + fr;
      if (col >= N) continue;
      float bv = 0.f;
      if (BIAS) bv = bias[col];
      #pragma unroll
      for (int r = 0; r < 4; r++) {
        const int row = r0 + r;
        if (row >= M) continue;
        float v = acc[i][j][r] + bv;
        if (ACT == 1) v = geluf(v);
        else if (ACT == 2) v = eluf(v);
        long long off;
        if (TROUT) off = cbase + (long long)col * ldc + row;
        else       off = cbase + (long long)row * ldc + col;
        if (OBF == 1)      ((bf16*)Cv)[off] = f2bf(v);
        else if (OBF == 2) atomicAdd(&((float*)Cv)[off], v);
        else               ((float*)Cv)[off] = v;
      }
    }
  }
}

// ---------------- small utility kernels ----------------
__global__ void k_zero(float* p, long long n) {
  long long i = (long long)blockIdx.x * blockDim.x + threadIdx.x;
  long long st = (long long)gridDim.x * blockDim.x;
  for (; i < n; i += st) p[i] = 0.f;
}

__global__ void k_zero_u32(unsigned* p, int n) {
  int i = blockIdx.x * 256 + threadIdx.x;
  if (i < n) p[i] = 0u;
}

__global__ void k_f2bf(const float* __restrict__ in, bf16* __restrict__ out, long long n) {
  long long i = (long long)blockIdx.x * 256 + threadIdx.x;
  if (i < n) out[i] = f2bf(in[i]);
}

__global__ void k_cat2(const float* __restrict__ a, const float* __restrict__ b,
                       float* __restrict__ o, int na, int nb) {
  int i = blockIdx.x * 256 + threadIdx.x;
  if (i < na) o[i] = a[i];
  else if (i < na + nb) o[i] = b[i - na];
}

__global__ void k_add_emb(const float* __restrict__ x, const float* __restrict__ ns,
                          bf16* __restrict__ h0, long long n4) {
  long long i = (long long)blockIdx.x * 256 + threadIdx.x;
  long long st = (long long)gridDim.x * 256;
  for (; i < n4; i += st) {
    float4 v = ((const float4*)x)[i];
    int d = (int)(i % (DE / 4)) * 4;
    short4_t o;
    o.x = bfbits(v.x + ns[d]);
    o.y = bfbits(v.y + ns[d + 1]);
    o.z = bfbits(v.z + ns[d + 2]);
    o.w = bfbits(v.w + ns[d + 3]);
    ((short4_t*)h0)[i] = o;
  }
}

// transpose f32 [R,C] -> bf16 [C,R]; R,C multiples of 32
__global__ void k_transpose_bf(const float* __restrict__ W, bf16* __restrict__ Wt, int R, int C) {
  __shared__ float t[32][33];
  int c0 = blockIdx.x * 32, r0 = blockIdx.y * 32;
  int x = threadIdx.x, y = threadIdx.y;
  #pragma unroll
  for (int j = 0; j < 32; j += 8)
    t[y + j][x] = W[(long long)(r0 + y + j) * C + c0 + x];
  __syncthreads();
  #pragma unroll
  for (int j = 0; j < 32; j += 8)
    Wt[(long long)(c0 + y + j) * R + r0 + x] = f2bf(t[x][y + j]);
}

// ---- CSR build (dst-indexed) ----
__global__ void k_count_dst(const int* __restrict__ ei, int E, int TOT, unsigned* __restrict__ cnt) {
  int e = blockIdx.x * 256 + threadIdx.x;
  if (e >= TOT) return;
  int d = (e < E) ? ei[E + e] : (e - E);
  atomicAdd(&cnt[d], 1u);
}

// single-block exclusive scan over n counts -> rowptr[0..n]
__global__ __launch_bounds__(1024)
void k_scan(const unsigned* __restrict__ cnt, int n, int* __restrict__ rowptr) {
  __shared__ unsigned tot[1024];
  int t = threadIdx.x;
  int ch = (n + 1023) / 1024;
  int beg = t * ch, end = beg + ch; if (end > n) end = n; if (beg > n) beg = n;
  unsigned s = 0;
  for (int i = beg; i < end; i++) s += cnt[i];
  tot[t] = s;
  __syncthreads();
  for (int o = 1; o < 1024; o <<= 1) {
    unsigned u = (t >= o) ? tot[t - o] : 0u;
    __syncthreads();
    tot[t] += u;
    __syncthreads();
  }
  unsigned run = tot[t] - s;   // exclusive prefix for this thread's chunk
  for (int i = beg; i < end; i++) { rowptr[i] = (int)run; run += cnt[i]; }
  if (t == 1023) rowptr[n] = (int)tot[1023];
}

__global__ void k_scatter(const int* __restrict__ ei, int E, int TOT,
                          const int* __restrict__ rowptr, unsigned* __restrict__ cursor,
                          int* __restrict__ esrc) {
  int e = blockIdx.x * 256 + threadIdx.x;
  if (e >= TOT) return;
  int s, d;
  if (e < E) { s = ei[e]; d = ei[E + e]; } else { s = d = e - E; }
  unsigned pos = atomicAdd(&cursor[d], 1u);
  esrc[rowptr[d] + pos] = s;
}

// es/ed per node: block = 512 threads, wave w = head
__global__ __launch_bounds__(512)
void k_esed(const bf16* __restrict__ hh, const float* __restrict__ asrc,
            const float* __restrict__ adst, float* __restrict__ es, float* __restrict__ ed) {
  int n = blockIdx.x;
  int h = threadIdx.x >> 6;
  int c = threadIdx.x & 63;
  float v = bf2f(hh[(long long)n * HD + h * 64 + c]);
  float s = v * asrc[h * 64 + c];
  float d = v * adst[h * 64 + c];
  #pragma unroll
  for (int o = 32; o; o >>= 1) { s += __shfl_down(s, o, 64); d += __shfl_down(d, o, 64); }
  if (c == 0) { es[n * 8 + h] = s; ed[n * 8 + h] = d; }
}

// fused GAT aggregation: one wave per destination node.
// pass 1: per-head max of LeakyReLU(es[src]+ed[dst]); pass 2: accumulate
// sum(exp * hh[src]) and sum(exp); epilogue: /den + bias (+ELU) -> bf16.
template<int ACT>
__global__ __launch_bounds__(256)
void k_gat_aggr(const int* __restrict__ rowptr, const int* __restrict__ esrc,
                const bf16* __restrict__ hh, const float* __restrict__ es,
                const float* __restrict__ ed, const float* __restrict__ gb,
                bf16* __restrict__ outp, int Nn)
{
  int w = blockIdx.x * 4 + (threadIdx.x >> 6);
  if (w >= Nn) return;
  int lane = threadIdx.x & 63;
  int h = lane >> 3;
  int beg = rowptr[w], end = rowptr[w + 1];
  float edh = ed[w * 8 + h];
  float mx = -3.0e38f;
  for (int e = beg; e < end; e++) {
    int s = esrc[e];
    float l = es[s * 8 + h] + edh;
    l = l > 0.f ? l : 0.2f * l;
    mx = fmaxf(mx, l);
  }
  float den = 0.f;
  float acc[8] = {0.f, 0.f, 0.f, 0.f, 0.f, 0.f, 0.f, 0.f};
  for (int e = beg; e < end; e++) {
    int s = esrc[e];
    float l = es[s * 8 + h] + edh;
    l = l > 0.f ? l : 0.2f * l;
    float ex = expf(l - mx);
    den += ex;
    short8 v = *(const short8*)(hh + (long long)s * HD + lane * 8);
    #pragma unroll
    for (int j = 0; j < 8; j++) {
      short sv = v[j];
      acc[j] += ex * bf2f(*reinterpret_cast<bf16*>(&sv));
    }
  }
  float rs = 1.f / (den + 1e-16f);
  short8 o;
  #pragma unroll
  for (int j = 0; j < 8; j++) {
    float val = acc[j] * rs + gb[lane * 8 + j];
    if (ACT == 2) val = eluf(val);
    o[j] = bfbits(val);
  }
  *(short8*)(outp + (long long)w * HD + lane * 8) = o;
}

template<int ACT, int BIAS, int TOBF>
__global__ void k_postproc(float* __restrict__ acc, const float* __restrict__ bias,
                           bf16* __restrict__ obf, long long tot, int cols) {
  long long i = (long long)blockIdx.x * 256 + threadIdx.x;
  if (i >= tot) return;
  int c = (int)(i % cols);
  float v = acc[i];
  if (BIAS) v += bias[c];
  if (ACT == 1) v = geluf(v);
  if (TOBF) obf[i] = f2bf(v);
  else acc[i] = v;
}

// row softmax (in-place capable): scores bf16 [rows][NPAD], scale folded
__global__ __launch_bounds__(256)
void k_softmax_row(const bf16* s_all, bf16* a_all, int NV) {
  long long row = blockIdx.x;
  const bf16* s = s_all + row * NPAD;
  bf16* a = a_all + row * NPAD;
  int tid = threadIdx.x;
  __shared__ float red[4];
  float mx = -3.0e38f;
  for (int c = tid; c < NV; c += 256) mx = fmaxf(mx, bf2f(s[c]));
  #pragma unroll
  for (int o = 32; o; o >>= 1) mx = fmaxf(mx, __shfl_down(mx, o, 64));
  if ((tid & 63) == 0) red[tid >> 6] = mx;
  __syncthreads();
  mx = fmaxf(fmaxf(red[0], red[1]), fmaxf(red[2], red[3]));
  const float inv = 0.05590169943749474f;  // 1/sqrt(320)
  float sm = 0.f;
  for (int c = tid; c < NV; c += 256) sm += expf((bf2f(s[c]) - mx) * inv);
  #pragma unroll
  for (int o = 32; o; o >>= 1) sm += __shfl_down(sm, o, 64);
  __syncthreads();
  if ((tid & 63) == 0) red[tid >> 6] = sm;
  __syncthreads();
  sm = red[0] + red[1] + red[2] + red[3];
  float rs = 1.f / sm;
  for (int c = tid; c < NPAD; c += 256) {
    float v = (c < NV) ? expf((bf2f(s[c]) - mx) * inv) * rs : 0.f;
    a[c] = f2bf(v);
  }
}

// LayerNorm(a+b) row of DE, optional bf16 dup
template<int WB>
__global__ __launch_bounds__(256)
void k_ln(const float* __restrict__ a, const float* __restrict__ b,
          const float* __restrict__ g, const float* __restrict__ bt,
          float* __restrict__ out, bf16* __restrict__ obf) {
  long long row = blockIdx.x;
  __shared__ float xs[DE];
  __shared__ float red[4];
  int tid = threadIdx.x;
  float sum = 0.f;
  for (int c = tid; c < DE; c += 256) {
    float v = a[row * DE + c] + b[row * DE + c];
    xs[c] = v; sum += v;
  }
  #pragma unroll
  for (int o = 32; o; o >>= 1) sum += __shfl_down(sum, o, 64);
  if ((tid & 63) == 0) red[tid >> 6] = sum;
  __syncthreads();
  float mean = (red[0] + red[1] + red[2] + red[3]) * (1.f / DE);
  float vs = 0.f;
  for (int c = tid; c < DE; c += 256) { float t = xs[c] - mean; vs += t * t; }
  #pragma unroll
  for (int o = 32; o; o >>= 1) vs += __shfl_down(vs, o, 64);
  __syncthreads();
  if ((tid & 63) == 0) red[tid >> 6] = vs;
  __syncthreads();
  float var = (red[0] + red[1] + red[2] + red[3]) * (1.f / DE);
  float sc = rsqrtf(var + 1e-5f);
  for (int c = tid; c < DE; c += 256) {
    float v = (xs[c] - mean) * sc * g[c] + bt[c];
    out[row * DE + c] = v;
    if (WB) obf[row * DE + c] = f2bf(v);
  }
}

// ---------------- host ----------------
extern "C" void kernel_launch(void* const* d_in, const int* in_sizes, int n_in,
                              void* d_out, int out_size, void* d_ws, size_t ws_size,
                              hipStream_t stream)
{
  const float* x       = (const float*)d_in[0];
  const int*   ei      = (const int*)d_in[1];
  const float* ns_emb  = (const float*)d_in[2];
  const float* gat_w0  = (const float*)d_in[3];
  const float* gat_wr  = (const float*)d_in[4];
  const float* a_src   = (const float*)d_in[5];
  const float* a_dst   = (const float*)d_in[6];
  const float* gat_b   = (const float*)d_in[7];
  const float* proj_w1 = (const float*)d_in[8];
  const float* proj_b1 = (const float*)d_in[9];
  const float* proj_w2 = (const float*)d_in[10];
  const float* proj_b2 = (const float*)d_in[11];
  const float* queries = (const float*)d_in[12];
  const float* wq = (const float*)d_in[13]; const float* bq = (const float*)d_in[14];
  const float* wk = (const float*)d_in[15]; const float* bk = (const float*)d_in[16];
  const float* wv = (const float*)d_in[17]; const float* bv = (const float*)d_in[18];
  const float* wo = (const float*)d_in[19]; const float* bo = (const float*)d_in[20];
  const float* ln1g = (const float*)d_in[21]; const float* ln1b = (const float*)d_in[22];
  const float* fw1 = (const float*)d_in[23]; const float* fb1 = (const float*)d_in[24];
  const float* fw2 = (const float*)d_in[25]; const float* fb2 = (const float*)d_in[26];
  const float* ln2g = (const float*)d_in[27]; const float* ln2b = (const float*)d_in[28];
  float* out = (float*)d_out;

  const int N = in_sizes[0] / DE;   // 30000
  const int E = in_sizes[1] / 2;    // 90000
  const int TOT = E + N;            // 120000
  const int MT2 = (N + 255) / 256;  // 256-tile M count (118)

  char* base = (char*)d_ws;
  size_t off = 0;
  auto AL = [&](size_t bytes) -> void* {
    void* p = base + off;
    off += (bytes + 255) & ~(size_t)255;
    return p;
  };
  bf16* wt_g0 = (bf16*)AL((size_t)HD * DE * 2);
  bf16* wt_g1 = (bf16*)AL((size_t)HD * HD * 2);
  bf16* wt_g2 = (bf16*)AL((size_t)HD * HD * 2);
  bf16* wt_p1 = (bf16*)AL((size_t)HD * HD * 2);
  bf16* wt_p2 = (bf16*)AL((size_t)DE * HD * 2);
  bf16* wt_q  = (bf16*)AL((size_t)DE * DE * 2);
  bf16* wt_kv = (bf16*)AL((size_t)2 * DE * DE * 2);   // [5120][2560]
  bf16* wt_o  = (bf16*)AL((size_t)DE * DE * 2);
  bf16* wt_f1 = (bf16*)AL((size_t)4 * DE * DE * 2);
  bf16* wt_f2 = (bf16*)AL((size_t)4 * DE * DE * 2);
  float* bias_kv = (float*)AL((size_t)2 * DE * 4);
  bf16* big0  = (bf16*)AL((size_t)N * DE * 2);      // h0 -> hD
  bf16* big1  = (bf16*)AL((size_t)N * DE * 2);      // k
  bf16* vT    = (bf16*)AL((size_t)DE * NPAD * 2);
  // GAT scratch block; union'd with the scores buffer `sc` (used after GAT dies)
  const size_t scBytes = (size_t)8 * QNUM * NPAD * 2;               // 96.05 MB
  size_t gatBytes = 2 * (size_t)N * HD * 2 + 2 * (size_t)N * 8 * 4  // hhA,hB,es,edv
                  + (size_t)(N + 1) * 4 + (size_t)TOT * 4 + (size_t)N * 4 + 4096;
  char* gat_blk = (char*)AL(gatBytes > scBytes ? gatBytes : scBytes);
  bf16* hhA = (bf16*)gat_blk;
  bf16* hB  = hhA + (size_t)N * HD;
  float* es  = (float*)(hB + (size_t)N * HD);
  float* edv = es + (size_t)N * 8;
  int* rowptr = (int*)(edv + (size_t)N * 8);
  int* esrc   = rowptr + (N + 1);
  unsigned* cnt = (unsigned*)(esrc + TOT);
  bf16* sc = (bf16*)gat_blk;  // scores/attn [8][QNUM][NPAD]
  // small f32 pool (zeroed once; targets of split-K atomic GEMMs)
  float* q_f     = (float*)AL((size_t)QNUM * DE * 4);
  float* ctx_f   = (float*)AL((size_t)QNUM * DE * 4);
  float* attnout = (float*)AL((size_t)QNUM * DE * 4);
  float* f1_f    = (float*)AL((size_t)QNUM * 4 * DE * 4);
  float* f2_f    = (float*)AL((size_t)QNUM * DE * 4);
  bf16* qs_bf  = (bf16*)AL((size_t)QNUM * DE * 2);
  bf16* q_bf   = (bf16*)AL((size_t)QNUM * DE * 2);
  bf16* ctx_bf = (bf16*)AL((size_t)QNUM * DE * 2);
  float* attended = (float*)AL((size_t)QNUM * DE * 4);
  bf16* att_bf = (bf16*)AL((size_t)QNUM * DE * 2);
  bf16* f1_bf  = (bf16*)AL((size_t)QNUM * 4 * DE * 2);

  dim3 blk(256);
  dim3 tblk(32, 8);

  // weight convert+transpose to bf16 [out,in]
  k_transpose_bf<<<dim3(HD / 32, DE / 32), tblk, 0, stream>>>(gat_w0, wt_g0, DE, HD);
  k_transpose_bf<<<dim3(HD / 32, HD / 32), tblk, 0, stream>>>(gat_wr, wt_g1, HD, HD);
  k_transpose_bf<<<dim3(HD / 32, HD / 32), tblk, 0, stream>>>(gat_wr + (size_t)HD * HD, wt_g2, HD, HD);
  k_transpose_bf<<<dim3(HD / 32, HD / 32), tblk, 0, stream>>>(proj_w1, wt_p1, HD, HD);
  k_transpose_bf<<<dim3(DE / 32, HD / 32), tblk, 0, stream>>>(proj_w2, wt_p2, HD, DE);
  k_transpose_bf<<<dim3(DE / 32, DE / 32), tblk, 0, stream>>>(wq, wt_q, DE, DE);
  k_transpose_bf<<<dim3(DE / 32, DE / 32), tblk, 0, stream>>>(wk, wt_kv, DE, DE);
  k_transpose_bf<<<dim3(DE / 32, DE / 32), tblk, 0, stream>>>(wv, wt_kv + (size_t)DE * DE, DE, DE);
  k_transpose_bf<<<dim3(DE / 32, DE / 32), tblk, 0, stream>>>(wo, wt_o, DE, DE);
  k_transpose_bf<<<dim3(4 * DE / 32, DE / 32), tblk, 0, stream>>>(fw1, wt_f1, DE, 4 * DE);
  k_transpose_bf<<<dim3(DE / 32, 4 * DE / 32), tblk, 0, stream>>>(fw2, wt_f2, 4 * DE, DE);
  k_cat2<<<dim3((2 * DE + 255) / 256), blk, 0, stream>>>(bk, bv, bias_kv, DE, DE);

  k_add_emb<<<dim3(2048), blk, 0, stream>>>(x, ns_emb, big0, (long long)N * DE / 4);
  k_f2bf<<<dim3((QNUM * DE + 255) / 256), blk, 0, stream>>>(queries, qs_bf, (long long)QNUM * DE);
  {
    long long pool = (long long)QNUM * DE * 4 + (long long)QNUM * 4 * DE;
    k_zero<<<dim3(1024), blk, 0, stream>>>(q_f, pool);
  }

  // ---- CSR build (once; reused by all 3 GAT layers) ----
  k_zero_u32<<<dim3((N + 255) / 256), blk, 0, stream>>>(cnt, N);
  k_count_dst<<<dim3((TOT + 255) / 256), blk, 0, stream>>>(ei, E, TOT, cnt);
  k_scan<<<dim3(1), dim3(1024), 0, stream>>>(cnt, N, rowptr);
  k_zero_u32<<<dim3((N + 255) / 256), blk, 0, stream>>>(cnt, N);
  k_scatter<<<dim3((TOT + 255) / 256), blk, 0, stream>>>(ei, E, TOT, rowptr, cnt, esrc);

  // ---- GAT layers ----
  const bf16* gw[3] = { wt_g0, wt_g1, wt_g2 };
  for (int l = 0; l < 3; l++) {
    const bf16* Ain = (l == 0) ? big0 : hB;
    int Kd = (l == 0) ? DE : HD;
    k_gemm256<0,0,0><<<dim3(2, MT2), dim3(512), 0, stream>>>(Ain, gw[l], nullptr, hhA,
        nullptr, 0, 8, N, HD, HD, Kd, Kd, Kd, HD, 0, 0, 0);
    k_esed<<<dim3(N), dim3(512), 0, stream>>>(hhA, a_src + l * HD, a_dst + l * HD, es, edv);
    if (l < 2)
      k_gat_aggr<2><<<dim3((N + 3) / 4), blk, 0, stream>>>(rowptr, esrc, hhA, es, edv,
          gat_b + l * HD, hB, N);
    else
      k_gat_aggr<0><<<dim3((N + 3) / 4), blk, 0, stream>>>(rowptr, esrc, hhA, es, edv,
          gat_b + l * HD, hB, N);
  }

  // ---- projection ----
  k_gemm256<1,1,0><<<dim3(2, MT2), dim3(512), 0, stream>>>(hB, wt_p1, proj_b1, hhA,
      nullptr, 0, 8, N, HD, HD, HD, HD, HD, HD, 0, 0, 0);
  k_gemm256<0,1,0><<<dim3(10, MT2), dim3(512), 0, stream>>>(hhA, wt_p2, proj_b2, big0,
      nullptr, 0, 8, N, DE, DE, HD, HD, HD, DE, 0, 0, 0);

  // ---- q (split-K), fused k+v (k -> big1 normal, v -> vT transposed), GM=16 ----
  k_gemm_nt<0,0,2,0><<<dim3(20, 2, 8), blk, 0, stream>>>(qs_bf, wt_q, nullptr, q_f,
      QNUM, DE, DE, DE, DE, DE, 0, 0, 0, 8, 320);
  k_postproc<0,1,1><<<dim3((QNUM * DE + 255) / 256), blk, 0, stream>>>(q_f, bq, q_bf,
      (long long)QNUM * DE, DE);
  k_gemm256<0,1,1><<<dim3(20, MT2), dim3(512), 0, stream>>>(big0, wt_kv, bias_kv, big1,
      vT, DE, 16, N, 2 * DE, 2 * DE, DE, DE, DE, DE, 0, 0, 0);

  // ---- scores, softmax, ctx (split-K 32) ----
  k_gemm256<0,0,0><<<dim3((NPAD + 255) / 256, 1, 8), dim3(512), 0, stream>>>(q_bf, big1, nullptr, sc,
      nullptr, 0, 8, QNUM, NPAD, N, ADHD, DE, DE, NPAD, 320, 320, (long long)QNUM * NPAD);
  k_softmax_row<<<dim3(8 * QNUM), blk, 0, stream>>>(sc, sc, N);
  k_gemm_nt<0,0,2,0><<<dim3(3, 2, 8 * 32), blk, 0, stream>>>(sc, vT, nullptr, ctx_f,
      QNUM, ADHD, NPAD, NPAD, NPAD, DE, (long long)QNUM * NPAD, (long long)ADHD * NPAD, 320, 32, 960);
  k_postproc<0,0,1><<<dim3((QNUM * DE + 255) / 256), blk, 0, stream>>>(ctx_f, nullptr, ctx_bf,
      (long long)QNUM * DE, DE);

  // ---- output projection + LN1 ----
  k_gemm_nt<0,0,2,0><<<dim3(20, 2, 8), blk, 0, stream>>>(ctx_bf, wt_o, nullptr, attnout,
      QNUM, DE, DE, DE, DE, DE, 0, 0, 0, 8, 320);
  k_postproc<0,1,0><<<dim3((QNUM * DE + 255) / 256), blk, 0, stream>>>(attnout, bo, nullptr,
      (long long)QNUM * DE, DE);
  k_ln<1><<<dim3(QNUM), blk, 0, stream>>>(queries, attnout, ln1g, ln1b, attended, att_bf);

  // ---- FFN + LN2 ----
  k_gemm_nt<0,0,2,0><<<dim3(80, 2, 4), blk, 0, stream>>>(att_bf, wt_f1, nullptr, f1_f,
      QNUM, 4 * DE, DE, DE, DE, 4 * DE, 0, 0, 0, 4, 640);
  k_postproc<1,1,1><<<dim3((QNUM * 4 * DE + 255) / 256), blk, 0, stream>>>(f1_f, fb1, f1_bf,
      (long long)QNUM * 4 * DE, 4 * DE);
  k_gemm_nt<0,0,2,0><<<dim3(20, 2, 8), blk, 0, stream>>>(f1_bf, wt_f2, nullptr, f2_f,
      QNUM, DE, 4 * DE, 4 * DE, 4 * DE, DE, 0, 0, 0, 8, 1280);
  k_postproc<0,1,0><<<dim3((QNUM * DE + 255) / 256), blk, 0, stream>>>(f2_f, fb2, nullptr,
      (long long)QNUM * DE, DE);
  k_ln<0><<<dim3(QNUM), blk, 0, stream>>>(attended, f2_f, ln2g, ln2b, out, nullptr);
}